// Round 2
// baseline (2318.800 us; speedup 1.0000x reference)
//
#include <hip/hip_runtime.h>

#define S_LEN 2048
#define DMODEL 2048
#define NH 16
#define NKV 4
#define HD 128
#define NE 8
#define FF 2048
#define QKV_N 3072   // (H + 2*KV) * HD
#define SKP 40       // padded LDS row stride (bf16 elems): 32 + 8

typedef __attribute__((ext_vector_type(8))) short short8;
typedef __attribute__((ext_vector_type(4))) float f32x4;

__device__ inline unsigned short f2bf(float f) {
  unsigned int u = __builtin_bit_cast(unsigned int, f);
  u += 0x7fffu + ((u >> 16) & 1u);
  return (unsigned short)(u >> 16);
}
__device__ inline float bf2f(unsigned short h) {
  unsigned int u = ((unsigned int)h) << 16;
  return __builtin_bit_cast(float, u);
}
__device__ inline void split2(float v, unsigned short& h, unsigned short& l) {
  h = f2bf(v);
  l = f2bf(v - bf2f(h));
}

// ---------------- staging helpers (128x32 tiles, 256 threads) ----------------

__device__ inline void stage_rows_bf16(const unsigned short* __restrict__ src, int ld,
                                       long row0, int k0, unsigned short* dst,
                                       int rows_valid) {
  int t = threadIdx.x;
  int r = t >> 1, half = t & 1;
  uint4 v0 = make_uint4(0, 0, 0, 0), v1 = v0;
  if (r < rows_valid) {
    const uint4* p = (const uint4*)(src + (size_t)(row0 + r) * ld + k0 + half * 16);
    v0 = p[0]; v1 = p[1];
  }
  uint4* q = (uint4*)(dst + r * SKP + half * 16);
  q[0] = v0; q[1] = v1;
}

__device__ inline void stage_gather_bf16(const unsigned short* __restrict__ src, int ld,
                                         const int* __restrict__ toks, int nvalid,
                                         int k0, unsigned short* dst) {
  int t = threadIdx.x;
  int r = t >> 1, half = t & 1;
  uint4 v0 = make_uint4(0, 0, 0, 0), v1 = v0;
  if (r < nvalid) {
    int row = toks[r];
    const uint4* p = (const uint4*)(src + (size_t)row * ld + k0 + half * 16);
    v0 = p[0]; v1 = p[1];
  }
  uint4* q = (uint4*)(dst + r * SKP + half * 16);
  q[0] = v0; q[1] = v1;
}

// f32 B [K, ldb] row-major -> Bs[n][k] single bf16
__device__ inline void stage_bT_f32(const float* __restrict__ B, int ldb, int k0, int n0,
                                    unsigned short* dst) {
  int t = threadIdx.x;
  int kk = t >> 3;
  int ng = (t & 7) * 16;
  const float4* p = (const float4*)(B + (size_t)(k0 + kk) * ldb + n0 + ng);
  float4 f0 = p[0], f1 = p[1], f2 = p[2], f3 = p[3];
  float v[16] = {f0.x, f0.y, f0.z, f0.w, f1.x, f1.y, f1.z, f1.w,
                 f2.x, f2.y, f2.z, f2.w, f3.x, f3.y, f3.z, f3.w};
#pragma unroll
  for (int i = 0; i < 16; i++) dst[(ng + i) * SKP + kk] = f2bf(v[i]);
}

// f32 B [K, ldb] row-major -> Bs_hi[n][k], Bs_lo[n][k] (split)
__device__ inline void stage_bT_f32_split(const float* __restrict__ B, int ldb, int k0,
                                          int n0, unsigned short* dh, unsigned short* dl) {
  int t = threadIdx.x;
  int kk = t >> 3;
  int ng = (t & 7) * 16;
  const float4* p = (const float4*)(B + (size_t)(k0 + kk) * ldb + n0 + ng);
  float4 f0 = p[0], f1 = p[1], f2 = p[2], f3 = p[3];
  float v[16] = {f0.x, f0.y, f0.z, f0.w, f1.x, f1.y, f1.z, f1.w,
                 f2.x, f2.y, f2.z, f2.w, f3.x, f3.y, f3.z, f3.w};
#pragma unroll
  for (int i = 0; i < 16; i++) {
    unsigned short hh, ll;
    split2(v[i], hh, ll);
    dh[(ng + i) * SKP + kk] = hh;
    dl[(ng + i) * SKP + kk] = ll;
  }
}

// ---------------- MFMA core ----------------

__device__ inline void mma16(const unsigned short* As, const unsigned short* Bs,
                             int wr, int wc, f32x4 acc[4][4]) {
  int l = threadIdx.x & 63;
  int lr = l & 15, lg = l >> 4;
  short8 a[4], b[4];
#pragma unroll
  for (int m = 0; m < 4; m++)
    a[m] = *(const short8*)(As + (size_t)(wr + m * 16 + lr) * SKP + lg * 8);
#pragma unroll
  for (int n = 0; n < 4; n++)
    b[n] = *(const short8*)(Bs + (size_t)(wc + n * 16 + lr) * SKP + lg * 8);
#pragma unroll
  for (int m = 0; m < 4; m++)
#pragma unroll
    for (int n = 0; n < 4; n++)
      acc[m][n] = __builtin_amdgcn_mfma_f32_16x16x32_bf16(a[m], b[n], acc[m][n], 0, 0, 0);
}

__device__ inline void mma16_dual(const unsigned short* As, const unsigned short* Bs1,
                                  const unsigned short* Bs2, int wr, int wc,
                                  f32x4 acc1[4][4], f32x4 acc2[4][4]) {
  int l = threadIdx.x & 63;
  int lr = l & 15, lg = l >> 4;
  short8 a[4], b1[4], b2[4];
#pragma unroll
  for (int m = 0; m < 4; m++)
    a[m] = *(const short8*)(As + (size_t)(wr + m * 16 + lr) * SKP + lg * 8);
#pragma unroll
  for (int n = 0; n < 4; n++) {
    b1[n] = *(const short8*)(Bs1 + (size_t)(wc + n * 16 + lr) * SKP + lg * 8);
    b2[n] = *(const short8*)(Bs2 + (size_t)(wc + n * 16 + lr) * SKP + lg * 8);
  }
#pragma unroll
  for (int m = 0; m < 4; m++)
#pragma unroll
    for (int n = 0; n < 4; n++) {
      acc1[m][n] = __builtin_amdgcn_mfma_f32_16x16x32_bf16(a[m], b1[n], acc1[m][n], 0, 0, 0);
      acc2[m][n] = __builtin_amdgcn_mfma_f32_16x16x32_bf16(a[m], b2[n], acc2[m][n], 0, 0, 0);
    }
}

// 3-pass split product: acc += Ah*Bh + Ah*Bl + Al*Bh
__device__ inline void mma16_split(const unsigned short* Ash, const unsigned short* Asl,
                                   const unsigned short* Bsh, const unsigned short* Bsl,
                                   int wr, int wc, f32x4 acc[4][4]) {
  mma16(Ash, Bsh, wr, wc, acc);
  mma16(Ash, Bsl, wr, wc, acc);
  mma16(Asl, Bsh, wr, wc, acc);
}

// ---------------- attention-path GEMMs (fp32-emulated) ----------------

// qkv = clip(h1 @ wqkv, +-8), fp32 out
__global__ __launch_bounds__(256) void k_qkv_s(const unsigned short* __restrict__ Ah,
                                               const unsigned short* __restrict__ Al,
                                               const float* __restrict__ B,
                                               float* __restrict__ C) {
  __shared__ unsigned short Ash[128 * SKP], Asl[128 * SKP], Bsh[128 * SKP], Bsl[128 * SKP];
  int row0 = blockIdx.y * 128, col0 = blockIdx.x * 128;
  int w = threadIdx.x >> 6;
  int wr = (w >> 1) * 64, wc = (w & 1) * 64;
  f32x4 acc[4][4] = {};
  for (int k0 = 0; k0 < DMODEL; k0 += 32) {
    __syncthreads();
    stage_rows_bf16(Ah, DMODEL, row0, k0, Ash, 128);
    stage_rows_bf16(Al, DMODEL, row0, k0, Asl, 128);
    stage_bT_f32_split(B, QKV_N, k0, col0, Bsh, Bsl);
    __syncthreads();
    mma16_split(Ash, Asl, Bsh, Bsl, wr, wc, acc);
  }
  int l = threadIdx.x & 63;
  int er = wr + ((l >> 4) << 2), ec = wc + (l & 15);
#pragma unroll
  for (int m = 0; m < 4; m++)
#pragma unroll
    for (int n = 0; n < 4; n++)
#pragma unroll
      for (int r = 0; r < 4; r++) {
        float v = acc[m][n][r];
        v = fminf(fmaxf(v, -8.f), 8.f);
        C[(size_t)(row0 + er + m * 16 + r) * QKV_N + col0 + ec + n * 16] = v;
      }
}

// scores (fp32) = (Q_h @ K_h^T) * scale, causal blocks only; z = local head
__global__ __launch_bounds__(256) void k_qk_s(const unsigned short* __restrict__ qh,
                                              const unsigned short* __restrict__ ql,
                                              const unsigned short* __restrict__ kh,
                                              const unsigned short* __restrict__ kl,
                                              float* __restrict__ scf, int hbase) {
  if ((int)blockIdx.x > (int)blockIdx.y) return;
  int h = hbase + blockIdx.z;
  const unsigned short* Ah = qh + (size_t)h * S_LEN * HD;
  const unsigned short* Al = ql + (size_t)h * S_LEN * HD;
  const unsigned short* Bh = kh + (size_t)(h >> 2) * S_LEN * HD;
  const unsigned short* Bl = kl + (size_t)(h >> 2) * S_LEN * HD;
  float* Cc = scf + (size_t)blockIdx.z * S_LEN * S_LEN;
  __shared__ unsigned short Ash[128 * SKP], Asl[128 * SKP], Bsh[128 * SKP], Bsl[128 * SKP];
  int row0 = blockIdx.y * 128, col0 = blockIdx.x * 128;
  int w = threadIdx.x >> 6;
  int wr = (w >> 1) * 64, wc = (w & 1) * 64;
  f32x4 acc[4][4] = {};
  for (int k0 = 0; k0 < HD; k0 += 32) {
    __syncthreads();
    stage_rows_bf16(Ah, HD, row0, k0, Ash, 128);
    stage_rows_bf16(Al, HD, row0, k0, Asl, 128);
    stage_rows_bf16(Bh, HD, col0, k0, Bsh, 128);
    stage_rows_bf16(Bl, HD, col0, k0, Bsl, 128);
    __syncthreads();
    mma16_split(Ash, Asl, Bsh, Bsl, wr, wc, acc);
  }
  const float scale = 1.0f / 11.313708498984761f;  // 1/sqrt(128), fp32
  int l = threadIdx.x & 63;
  int er = wr + ((l >> 4) << 2), ec = wc + (l & 15);
#pragma unroll
  for (int m = 0; m < 4; m++)
#pragma unroll
    for (int n = 0; n < 4; n++)
#pragma unroll
      for (int r = 0; r < 4; r++)
        Cc[(size_t)(row0 + er + m * 16 + r) * S_LEN + col0 + ec + n * 16] =
            acc[m][n][r] * scale;
}

// softmax rows (fp32 in) -> P split bf16 (hi, lo); zeros above diagonal
__global__ __launch_bounds__(256) void k_sm_s(const float* __restrict__ scf,
                                              unsigned short* __restrict__ Ph,
                                              unsigned short* __restrict__ Pl) {
  int q = blockIdx.x, z = blockIdx.y;
  const float* row = scf + ((size_t)z * S_LEN + q) * S_LEN;
  int t = threadIdx.x;
  float4 a0 = ((const float4*)row)[t * 2];
  float4 a1 = ((const float4*)row)[t * 2 + 1];
  float v[8] = {a0.x, a0.y, a0.z, a0.w, a1.x, a1.y, a1.z, a1.w};
  float mx = -3.4e38f;
#pragma unroll
  for (int j = 0; j < 8; j++)
    if (t * 8 + j <= q) mx = fmaxf(mx, v[j]);
#pragma unroll
  for (int o = 32; o; o >>= 1) mx = fmaxf(mx, __shfl_down(mx, o));
  __shared__ float red[8];
  int wid = t >> 6;
  if ((t & 63) == 0) red[wid] = mx;
  __syncthreads();
  if (t == 0) red[4] = fmaxf(fmaxf(red[0], red[1]), fmaxf(red[2], red[3]));
  __syncthreads();
  mx = red[4];
  float s = 0.f;
#pragma unroll
  for (int j = 0; j < 8; j++) {
    float e = (t * 8 + j <= q) ? expf(v[j] - mx) : 0.f;
    v[j] = e; s += e;
  }
#pragma unroll
  for (int o = 32; o; o >>= 1) s += __shfl_down(s, o);
  if ((t & 63) == 0) red[wid] = s;
  __syncthreads();
  if (t == 0) red[5] = red[0] + red[1] + red[2] + red[3];
  __syncthreads();
  float inv = 1.f / red[5];
  uint4 hv, lv;
  unsigned short* hp = (unsigned short*)&hv;
  unsigned short* lp = (unsigned short*)&lv;
#pragma unroll
  for (int j = 0; j < 8; j++) split2(v[j] * inv, hp[j], lp[j]);
  ((uint4*)(Ph + ((size_t)z * S_LEN + q) * S_LEN))[t] = hv;
  ((uint4*)(Pl + ((size_t)z * S_LEN + q) * S_LEN))[t] = lv;
}

// attn_cols[h] = P @ V (split), out split bf16
__global__ __launch_bounds__(256) void k_pv_s(const unsigned short* __restrict__ Ph,
                                              const unsigned short* __restrict__ Pl,
                                              const float* __restrict__ qkv,
                                              unsigned short* __restrict__ ath,
                                              unsigned short* __restrict__ atl, int hbase) {
  int z = blockIdx.z;
  int h = hbase + z;
  const unsigned short* Ah = Ph + (size_t)z * S_LEN * S_LEN;
  const unsigned short* Al = Pl + (size_t)z * S_LEN * S_LEN;
  const float* B = qkv + (NH + NKV) * HD + (size_t)(h >> 2) * HD;  // ldb = QKV_N
  __shared__ unsigned short Ash[128 * SKP], Asl[128 * SKP], Bsh[128 * SKP], Bsl[128 * SKP];
  int row0 = blockIdx.y * 128;
  int Keff = (blockIdx.y + 1) * 128;
  int w = threadIdx.x >> 6;
  int wr = (w >> 1) * 64, wc = (w & 1) * 64;
  f32x4 acc[4][4] = {};
  for (int k0 = 0; k0 < Keff; k0 += 32) {
    __syncthreads();
    stage_rows_bf16(Ah, S_LEN, row0, k0, Ash, 128);
    stage_rows_bf16(Al, S_LEN, row0, k0, Asl, 128);
    stage_bT_f32_split(B, QKV_N, k0, 0, Bsh, Bsl);
    __syncthreads();
    mma16_split(Ash, Asl, Bsh, Bsl, wr, wc, acc);
  }
  int l = threadIdx.x & 63;
  int er = wr + ((l >> 4) << 2), ec = wc + (l & 15);
#pragma unroll
  for (int m = 0; m < 4; m++)
#pragma unroll
    for (int n = 0; n < 4; n++)
#pragma unroll
      for (int r = 0; r < 4; r++) {
        size_t idx = (size_t)(row0 + er + m * 16 + r) * DMODEL + h * HD + ec + n * 16;
        unsigned short hh, ll;
        split2(acc[m][n][r], hh, ll);
        ath[idx] = hh; atl[idx] = ll;
      }
}

// x1 = hidden + attn @ wo (split A, split B)
__global__ __launch_bounds__(256) void k_wo_s(const unsigned short* __restrict__ Ah,
                                              const unsigned short* __restrict__ Al,
                                              const float* __restrict__ B,
                                              const float* __restrict__ resid,
                                              float* __restrict__ x1) {
  __shared__ unsigned short Ash[128 * SKP], Asl[128 * SKP], Bsh[128 * SKP], Bsl[128 * SKP];
  int row0 = blockIdx.y * 128, col0 = blockIdx.x * 128;
  int w = threadIdx.x >> 6;
  int wr = (w >> 1) * 64, wc = (w & 1) * 64;
  f32x4 acc[4][4] = {};
  for (int k0 = 0; k0 < DMODEL; k0 += 32) {
    __syncthreads();
    stage_rows_bf16(Ah, DMODEL, row0, k0, Ash, 128);
    stage_rows_bf16(Al, DMODEL, row0, k0, Asl, 128);
    stage_bT_f32_split(B, DMODEL, k0, col0, Bsh, Bsl);
    __syncthreads();
    mma16_split(Ash, Asl, Bsh, Bsl, wr, wc, acc);
  }
  int l = threadIdx.x & 63;
  int er = wr + ((l >> 4) << 2), ec = wc + (l & 15);
#pragma unroll
  for (int m = 0; m < 4; m++)
#pragma unroll
    for (int n = 0; n < 4; n++)
#pragma unroll
      for (int r = 0; r < 4; r++) {
        size_t idx = (size_t)(row0 + er + m * 16 + r) * DMODEL + col0 + ec + n * 16;
        x1[idx] = resid[idx] + acc[m][n][r];
      }
}

// ---------------- MoE GEMMs (plain bf16) ----------------

__global__ __launch_bounds__(256) void k_moe1(const unsigned short* __restrict__ h2b,
                                              const float* __restrict__ w1,
                                              const float* __restrict__ v1,
                                              const int* __restrict__ cnt,
                                              const int* __restrict__ off,
                                              const int* __restrict__ ptok,
                                              unsigned short* __restrict__ g) {
  int e = blockIdx.z;
  int cntE = cnt[e];
  int m0 = blockIdx.y * 128;
  if (m0 >= cntE) return;
  int nvalid = min(128, cntE - m0);
  const int* toks = ptok + off[e] + m0;
  int col0 = blockIdx.x * 128;
  const float* B1 = w1 + (size_t)e * DMODEL * FF;
  const float* B2 = v1 + (size_t)e * DMODEL * FF;
  __shared__ unsigned short As[128 * SKP], Bs1[128 * SKP], Bs2[128 * SKP];
  int w = threadIdx.x >> 6;
  int wr = (w >> 1) * 64, wc = (w & 1) * 64;
  f32x4 acc1[4][4] = {}, acc2[4][4] = {};
  for (int k0 = 0; k0 < DMODEL; k0 += 32) {
    __syncthreads();
    stage_gather_bf16(h2b, DMODEL, toks, nvalid, k0, As);
    stage_bT_f32(B1, FF, k0, col0, Bs1);
    stage_bT_f32(B2, FF, k0, col0, Bs2);
    __syncthreads();
    mma16_dual(As, Bs1, Bs2, wr, wc, acc1, acc2);
  }
  int l = threadIdx.x & 63;
  int er = wr + ((l >> 4) << 2), ec = wc + (l & 15);
  size_t gbase = (size_t)off[e] + m0;
#pragma unroll
  for (int m = 0; m < 4; m++)
#pragma unroll
    for (int n = 0; n < 4; n++)
#pragma unroll
      for (int r = 0; r < 4; r++) {
        int rl = er + m * 16 + r;
        if (rl < nvalid) {
          float a = acc1[m][n][r];
          float s = a / (1.f + expf(-a));
          g[(gbase + rl) * FF + col0 + ec + n * 16] = f2bf(s * acc2[m][n][r]);
        }
      }
}

__global__ __launch_bounds__(256) void k_moe2(const unsigned short* __restrict__ g,
                                              const float* __restrict__ w2,
                                              const int* __restrict__ cnt,
                                              const int* __restrict__ off,
                                              const int* __restrict__ ptok,
                                              const float* __restrict__ pw,
                                              float* __restrict__ y) {
  int e = blockIdx.z;
  int cntE = cnt[e];
  int m0 = blockIdx.y * 128;
  if (m0 >= cntE) return;
  int nvalid = min(128, cntE - m0);
  long pbase = (long)off[e] + m0;
  int col0 = blockIdx.x * 128;
  const float* B = w2 + (size_t)e * FF * DMODEL;
  __shared__ unsigned short As[128 * SKP], Bs[128 * SKP];
  int w = threadIdx.x >> 6;
  int wr = (w >> 1) * 64, wc = (w & 1) * 64;
  f32x4 acc[4][4] = {};
  for (int k0 = 0; k0 < FF; k0 += 32) {
    __syncthreads();
    stage_rows_bf16(g, FF, pbase, k0, As, nvalid);
    stage_bT_f32(B, DMODEL, k0, col0, Bs);
    __syncthreads();
    mma16(As, Bs, wr, wc, acc);
  }
  int l = threadIdx.x & 63;
  int er = wr + ((l >> 4) << 2), ec = wc + (l & 15);
#pragma unroll
  for (int m = 0; m < 4; m++)
#pragma unroll
    for (int n = 0; n < 4; n++)
#pragma unroll
      for (int r = 0; r < 4; r++) {
        int rl = er + m * 16 + r;
        if (rl < nvalid) {
          long p = pbase + rl;
          int tk = ptok[p];
          atomicAdd(&y[(size_t)tk * DMODEL + col0 + ec + n * 16], acc[m][n][r] * pw[p]);
        }
      }
}

// ---------------- small kernels ----------------

// LN row; writes hi bf16 (always), lo bf16 (if obl), fp32 (if of)
__global__ __launch_bounds__(256) void k_ln(const float* __restrict__ x,
                                            const float* __restrict__ w,
                                            unsigned short* __restrict__ obh,
                                            unsigned short* __restrict__ obl,
                                            float* __restrict__ of) {
  int row = blockIdx.x;
  const float* xr = x + (size_t)row * DMODEL;
  float s = 0.f, ss = 0.f;
  for (int c = threadIdx.x; c < DMODEL; c += 256) {
    float v = xr[c];
    s += v; ss += v * v;
  }
#pragma unroll
  for (int o = 32; o; o >>= 1) { s += __shfl_down(s, o); ss += __shfl_down(ss, o); }
  __shared__ float rs[4], rss[4], mu_s, inv_s;
  int wid = threadIdx.x >> 6;
  if ((threadIdx.x & 63) == 0) { rs[wid] = s; rss[wid] = ss; }
  __syncthreads();
  if (threadIdx.x == 0) {
    float S1 = rs[0] + rs[1] + rs[2] + rs[3];
    float S2 = rss[0] + rss[1] + rss[2] + rss[3];
    float mu = S1 / DMODEL;
    mu_s = mu;
    inv_s = rsqrtf(S2 / DMODEL - mu * mu + 1e-5f);
  }
  __syncthreads();
  float mu = mu_s, inv = inv_s;
  for (int c = threadIdx.x; c < DMODEL; c += 256) {
    float v = (xr[c] - mu) * inv * w[c];
    unsigned short hh, ll;
    split2(v, hh, ll);
    obh[(size_t)row * DMODEL + c] = hh;
    if (obl) obl[(size_t)row * DMODEL + c] = ll;
    if (of) of[(size_t)row * DMODEL + c] = v;
  }
}

// RoPE with np-fp32-matched angle chain; writes split q, k
__global__ void k_rope2(const float* __restrict__ qkv, unsigned short* __restrict__ qh,
                        unsigned short* __restrict__ ql, unsigned short* __restrict__ kh,
                        unsigned short* __restrict__ kl) {
  int t = blockIdx.x;
  int d = threadIdx.x;  // 0..63
  // reference: inv_freq = 1.0f / powf(theta, d/64.f); ang = float(t) * inv_freq
  float pf = (float)pow(500000.0, (double)d * (1.0 / 64.0));  // correctly-rounded f32
  float invf = 1.0f / pf;                                      // IEEE f32 divide
  float ang = (float)t * invf;                                 // IEEE f32 multiply
  float cs = (float)cos((double)ang);
  float sn = (float)sin((double)ang);
  const float* row = qkv + (size_t)t * QKV_N;
  unsigned short hh, ll;
#pragma unroll
  for (int hq = 0; hq < NH; hq++) {
    float a = row[hq * HD + d], b = row[hq * HD + d + 64];
    size_t base = ((size_t)hq * S_LEN + t) * HD;
    split2(a * cs - b * sn, hh, ll); qh[base + d] = hh; ql[base + d] = ll;
    split2(b * cs + a * sn, hh, ll); qh[base + d + 64] = hh; ql[base + d + 64] = ll;
  }
#pragma unroll
  for (int kv = 0; kv < NKV; kv++) {
    float a = row[NH * HD + kv * HD + d], b = row[NH * HD + kv * HD + d + 64];
    size_t base = ((size_t)kv * S_LEN + t) * HD;
    split2(a * cs - b * sn, hh, ll); kh[base + d] = hh; kl[base + d] = ll;
    split2(b * cs + a * sn, hh, ll); kh[base + d + 64] = hh; kl[base + d + 64] = ll;
  }
}

__global__ __launch_bounds__(256) void k_router(const float* __restrict__ h2,
                                                const float* __restrict__ rw,
                                                int* __restrict__ topi,
                                                float* __restrict__ topw,
                                                int* __restrict__ cnt) {
  int t = blockIdx.x;
  __shared__ float hs[DMODEL];
  __shared__ float lg[NE];
  for (int c = threadIdx.x; c < DMODEL; c += 256) hs[c] = h2[(size_t)t * DMODEL + c];
  __syncthreads();
  int grp = threadIdx.x >> 5;
  int ln = threadIdx.x & 31;
  float p = 0.f;
  for (int c = ln; c < DMODEL; c += 32) p += hs[c] * rw[(size_t)grp * DMODEL + c];
#pragma unroll
  for (int o = 16; o; o >>= 1) p += __shfl_down(p, o, 32);
  if (ln == 0) lg[grp] = p;
  __syncthreads();
  if (threadIdx.x == 0) {
    float l0 = -3.4e38f; int i0 = 0;
    for (int e = 0; e < NE; e++)
      if (lg[e] > l0) { l0 = lg[e]; i0 = e; }
    float l1 = -3.4e38f; int i1 = 0;
    for (int e = 0; e < NE; e++)
      if (e != i0 && lg[e] > l1) { l1 = lg[e]; i1 = e; }
    float z = expf(l1 - l0);
    topi[t * 2] = i0; topi[t * 2 + 1] = i1;
    topw[t * 2] = 1.f / (1.f + z); topw[t * 2 + 1] = z / (1.f + z);
    atomicAdd(&cnt[i0], 1);
    atomicAdd(&cnt[i1], 1);
  }
}

__global__ void k_scan(const int* __restrict__ cnt, int* __restrict__ off) {
  if (threadIdx.x == 0 && blockIdx.x == 0) {
    int o = 0;
    for (int e = 0; e < NE; e++) { off[e] = o; o += cnt[e]; }
    off[NE] = o;
  }
}

__global__ void k_fill(const int* __restrict__ topi, const float* __restrict__ topw,
                       const int* __restrict__ off, int* __restrict__ fill,
                       int* __restrict__ ptok, float* __restrict__ pw) {
  int t = blockIdx.x * blockDim.x + threadIdx.x;
  if (t >= S_LEN) return;
#pragma unroll
  for (int j = 0; j < 2; j++) {
    int e = topi[t * 2 + j];
    int p = atomicAdd(&fill[e], 1);
    ptok[off[e] + p] = t;
    pw[off[e] + p] = topw[t * 2 + j];
  }
}

__global__ void k_final(const float* __restrict__ x1, const float* __restrict__ y,
                        float* __restrict__ out) {
  int i = blockIdx.x * blockDim.x + threadIdx.x;
  float4 a = ((const float4*)x1)[i];
  float4 b = ((const float4*)y)[i];
  ((float4*)out)[i] = make_float4(a.x + b.x, a.y + b.y, a.z + b.z, a.w + b.w);
}

// ---------------- launch ----------------

extern "C" void kernel_launch(void* const* d_in, const int* in_sizes, int n_in,
                              void* d_out, int out_size, void* d_ws, size_t ws_size,
                              hipStream_t stream) {
  (void)in_sizes; (void)n_in; (void)out_size; (void)ws_size;
  const float* x = (const float*)d_in[0];
  const float* ln1w = (const float*)d_in[2];
  const float* ln2w = (const float*)d_in[3];
  const float* wqkv = (const float*)d_in[4];
  const float* wo = (const float*)d_in[5];
  const float* rw = (const float*)d_in[6];
  const float* w1 = (const float*)d_in[7];
  const float* v1 = (const float*)d_in[8];
  const float* w2 = (const float*)d_in[9];
  float* out = (float*)d_out;

  char* wsb = (char*)d_ws;
  const size_t MB8 = (size_t)S_LEN * DMODEL * 2;  // 8,388,608
  // layout (with aliasing; phases don't overlap):
  unsigned short* h1h = (unsigned short*)(wsb + 0);           // [S,D] bf16
  unsigned short* h1l = (unsigned short*)(wsb + MB8);         // [S,D] bf16
  unsigned short* Ph  = (unsigned short*)(wsb + 0);           // alias over h1 (attn phase)
  float* qkvb = (float*)(wsb + 2 * MB8);                      // [S,3072] f32 (25.2MB)
  unsigned short* qh = (unsigned short*)(wsb + 2 * MB8 + 25165824);
  unsigned short* ql = (unsigned short*)(wsb + 3 * MB8 + 25165824);
  float* y = (float*)(wsb + 2 * MB8 + 25165824);              // alias over qh+ql (MoE phase)
  unsigned short* kh = (unsigned short*)(wsb + 4 * MB8 + 25165824);
  unsigned short* kl = (unsigned short*)(wsb + 4 * MB8 + 25165824 + 2097152);
  char* scbase = wsb + 4 * MB8 + 25165824 + 4194304;
  float* scf = (float*)scbase;                                 // [2,S,S] f32 (33.5MB)
  float* h2f = (float*)scbase;                                 // alias (post-attn)
  unsigned short* g = (unsigned short*)(scbase + 2 * MB8);     // alias (MoE phase)
  unsigned short* Pl = (unsigned short*)(scbase + 33554432);   // [2,S,S] bf16 (16.8MB)
  unsigned short* ath = (unsigned short*)(scbase + 33554432 + 2 * MB8);
  unsigned short* atl = (unsigned short*)(scbase + 33554432 + 3 * MB8);
  float* x1 = (float*)(scbase + 33554432 + 4 * MB8);           // 16.8MB
  unsigned short* h2b = (unsigned short*)(scbase + 33554432 + 6 * MB8);
  char* small = scbase + 33554432 + 7 * MB8;
  int* topi = (int*)small;                    // 4096 ints
  float* topw = (float*)(small + 16384);      // 4096 f32
  int* ptok = (int*)(small + 32768);          // 4096 ints
  float* pw = (float*)(small + 49152);        // 4096 f32
  int* meta = (int*)(small + 65536);
  int* cnt = meta;
  int* fillc = meta + 8;
  int* off = meta + 16;

  // ---- attention sublayer (fp32-emulated) ----
  k_ln<<<S_LEN, 256, 0, stream>>>(x, ln1w, h1h, h1l, (float*)nullptr);
  k_qkv_s<<<dim3(QKV_N / 128, S_LEN / 128), 256, 0, stream>>>(h1h, h1l, wqkv, qkvb);
  k_rope2<<<S_LEN, 64, 0, stream>>>(qkvb, qh, ql, kh, kl);
  for (int c = 0; c < 8; c++) {
    k_qk_s<<<dim3(16, 16, 2), 256, 0, stream>>>(qh, ql, kh, kl, scf, 2 * c);
    k_sm_s<<<dim3(S_LEN, 2), 256, 0, stream>>>(scf, Ph, Pl);
    k_pv_s<<<dim3(1, 16, 2), 256, 0, stream>>>(Ph, Pl, qkvb, ath, atl, 2 * c);
  }
  k_wo_s<<<dim3(16, 16), 256, 0, stream>>>(ath, atl, wo, x, x1);

  // ---- MoE sublayer ----
  k_ln<<<S_LEN, 256, 0, stream>>>(x1, ln2w, h2b, (unsigned short*)nullptr, h2f);
  hipMemsetAsync(y, 0, (size_t)S_LEN * DMODEL * 4, stream);  // y aliases q (dead now)
  hipMemsetAsync(meta, 0, 64, stream);
  k_router<<<S_LEN, 256, 0, stream>>>(h2f, rw, topi, topw, cnt);
  k_scan<<<1, 64, 0, stream>>>(cnt, off);
  k_fill<<<8, 256, 0, stream>>>(topi, topw, off, fillc, ptok, pw);
  k_moe1<<<dim3(16, 16, 8), 256, 0, stream>>>(h2b, w1, v1, cnt, off, ptok, g);
  k_moe2<<<dim3(16, 16, 8), 256, 0, stream>>>(g, w2, cnt, off, ptok, pw, y);
  k_final<<<(S_LEN * DMODEL / 4) / 256, 256, 0, stream>>>(x1, y, out);
}

// Round 3
// 1173.674 us; speedup vs baseline: 1.9757x; 1.9757x over previous
//
#include <hip/hip_runtime.h>

#define S_LEN 2048
#define DMODEL 2048
#define NH 16
#define NKV 4
#define HD 128
#define NE 8
#define FF 2048
#define QKV_N 3072   // (H + 2*KV) * HD

typedef __attribute__((ext_vector_type(8))) short short8;
typedef __attribute__((ext_vector_type(4))) float f32x4;

__device__ inline unsigned short f2bf(float f) {
  unsigned int u = __builtin_bit_cast(unsigned int, f);
  u += 0x7fffu + ((u >> 16) & 1u);
  return (unsigned short)(u >> 16);
}
__device__ inline float bf2f(unsigned short h) {
  unsigned int u = ((unsigned int)h) << 16;
  return __builtin_bit_cast(float, u);
}
__device__ inline void split2(float v, unsigned short& h, unsigned short& l) {
  h = f2bf(v);
  l = f2bf(v - bf2f(h));
}

// ======== LDS tile: [128 rows][32 k] bf16, linear stride 32, XOR-quad swizzle ========
// element (row, k=8q+j) stored at row*32 + ((q ^ s(row))<<3) + j, s(row)=(row^(row>>2))&3.
// All LDS ops are b128 and bank-balanced (8 distinct quad-spans x 8 lanes each).

// bf16 rows [*, ld] -> tile
__device__ inline void stage_rows(const unsigned short* __restrict__ src, int ld,
                                  long row0, int k0, unsigned short* dst) {
  int t = threadIdx.x;
  int r = t >> 2, q = t & 3;
  int s = (r ^ (r >> 2)) & 3;  // same for r and r+64
  uint4 v0 = *(const uint4*)(src + (size_t)(row0 + r) * ld + k0 + q * 8);
  uint4 v1 = *(const uint4*)(src + (size_t)(row0 + r + 64) * ld + k0 + q * 8);
  *(uint4*)(dst + r * 32 + ((q ^ s) << 3)) = v0;
  *(uint4*)(dst + (r + 64) * 32 + ((q ^ s) << 3)) = v1;
}

// gathered bf16 rows via token list
__device__ inline void stage_gather(const unsigned short* __restrict__ src, int ld,
                                    const int* __restrict__ toks, int nvalid,
                                    int k0, unsigned short* dst) {
  int t = threadIdx.x;
  int r = t >> 2, q = t & 3;
  int s = (r ^ (r >> 2)) & 3;
#pragma unroll
  for (int rr = 0; rr < 2; rr++) {
    int row = r + rr * 64;
    uint4 v = make_uint4(0, 0, 0, 0);
    if (row < nvalid)
      v = *(const uint4*)(src + (size_t)toks[row] * ld + k0 + q * 8);
    *(uint4*)(dst + row * 32 + ((q ^ s) << 3)) = v;
  }
}

// f32 B [K, ldb] -> tile[n][k] (transpose), k-gather: coalesced strided loads
__device__ inline void stage_bT(const float* __restrict__ B, long ldb, int k0, int n0,
                                unsigned short* dst) {
  int t = threadIdx.x;
  int n = t & 127, kg = t >> 7;
  const float* p = B + (size_t)(k0 + kg * 16) * ldb + n0 + n;
  unsigned short hb[16] __attribute__((aligned(16)));
#pragma unroll
  for (int i = 0; i < 16; i++) hb[i] = f2bf(p[(size_t)i * ldb]);
  int s = (n ^ (n >> 2)) & 3;
  int base = n * 32;
  *(uint4*)(dst + base + (((kg * 2) ^ s) << 3)) = ((const uint4*)hb)[0];
  *(uint4*)(dst + base + (((kg * 2 + 1) ^ s) << 3)) = ((const uint4*)hb)[1];
}

// f32 B [K, ldb] -> split tiles
__device__ inline void stage_bT_split(const float* __restrict__ B, long ldb, int k0, int n0,
                                      unsigned short* dh, unsigned short* dl) {
  int t = threadIdx.x;
  int n = t & 127, kg = t >> 7;
  const float* p = B + (size_t)(k0 + kg * 16) * ldb + n0 + n;
  unsigned short hb[16] __attribute__((aligned(16)));
  unsigned short lb[16] __attribute__((aligned(16)));
#pragma unroll
  for (int i = 0; i < 16; i++) split2(p[(size_t)i * ldb], hb[i], lb[i]);
  int s = (n ^ (n >> 2)) & 3;
  int base = n * 32;
  int q0 = (((kg * 2) ^ s) << 3), q1 = (((kg * 2 + 1) ^ s) << 3);
  *(uint4*)(dh + base + q0) = ((const uint4*)hb)[0];
  *(uint4*)(dh + base + q1) = ((const uint4*)hb)[1];
  *(uint4*)(dl + base + q0) = ((const uint4*)lb)[0];
  *(uint4*)(dl + base + q1) = ((const uint4*)lb)[1];
}

// ---------------- MFMA core: wave computes 64x64 via 4x4 frags ----------------

__device__ inline void mma16(const unsigned short* As, const unsigned short* Bs,
                             int wr, int wc, f32x4 acc[4][4]) {
  int l = threadIdx.x & 63;
  int lr = l & 15, lg = l >> 4;
  int qoff = ((lg ^ ((lr ^ (lr >> 2)) & 3)) << 3);
  short8 a[4], b[4];
#pragma unroll
  for (int m = 0; m < 4; m++)
    a[m] = *(const short8*)(As + (wr + m * 16 + lr) * 32 + qoff);
#pragma unroll
  for (int n = 0; n < 4; n++)
    b[n] = *(const short8*)(Bs + (wc + n * 16 + lr) * 32 + qoff);
#pragma unroll
  for (int m = 0; m < 4; m++)
#pragma unroll
    for (int n = 0; n < 4; n++)
      acc[m][n] = __builtin_amdgcn_mfma_f32_16x16x32_bf16(a[m], b[n], acc[m][n], 0, 0, 0);
}

__device__ inline void mma16_dual(const unsigned short* As, const unsigned short* Bs1,
                                  const unsigned short* Bs2, int wr, int wc,
                                  f32x4 acc1[4][4], f32x4 acc2[4][4]) {
  int l = threadIdx.x & 63;
  int lr = l & 15, lg = l >> 4;
  int qoff = ((lg ^ ((lr ^ (lr >> 2)) & 3)) << 3);
  short8 a[4], b1[4], b2[4];
#pragma unroll
  for (int m = 0; m < 4; m++)
    a[m] = *(const short8*)(As + (wr + m * 16 + lr) * 32 + qoff);
#pragma unroll
  for (int n = 0; n < 4; n++) {
    b1[n] = *(const short8*)(Bs1 + (wc + n * 16 + lr) * 32 + qoff);
    b2[n] = *(const short8*)(Bs2 + (wc + n * 16 + lr) * 32 + qoff);
  }
#pragma unroll
  for (int m = 0; m < 4; m++)
#pragma unroll
    for (int n = 0; n < 4; n++) {
      acc1[m][n] = __builtin_amdgcn_mfma_f32_16x16x32_bf16(a[m], b1[n], acc1[m][n], 0, 0, 0);
      acc2[m][n] = __builtin_amdgcn_mfma_f32_16x16x32_bf16(a[m], b2[n], acc2[m][n], 0, 0, 0);
    }
}

__device__ inline void mma16_split(const unsigned short* Ash, const unsigned short* Asl,
                                   const unsigned short* Bsh, const unsigned short* Bsl,
                                   int wr, int wc, f32x4 acc[4][4]) {
  mma16(Ash, Bsh, wr, wc, acc);
  mma16(Ash, Bsl, wr, wc, acc);
  mma16(Asl, Bsh, wr, wc, acc);
}

// ---------------- attention-path GEMMs (fp32-emulated) ----------------

__global__ __launch_bounds__(256) void k_qkv_s(const unsigned short* __restrict__ Ah,
                                               const unsigned short* __restrict__ Al,
                                               const float* __restrict__ B,
                                               float* __restrict__ C) {
  __shared__ unsigned short Ash[128 * 32], Asl[128 * 32], Bsh[128 * 32], Bsl[128 * 32];
  int row0 = blockIdx.y * 128, col0 = blockIdx.x * 128;
  int w = threadIdx.x >> 6;
  int wr = (w >> 1) * 64, wc = (w & 1) * 64;
  f32x4 acc[4][4] = {};
  for (int k0 = 0; k0 < DMODEL; k0 += 32) {
    __syncthreads();
    stage_rows(Ah, DMODEL, row0, k0, Ash);
    stage_rows(Al, DMODEL, row0, k0, Asl);
    stage_bT_split(B, QKV_N, k0, col0, Bsh, Bsl);
    __syncthreads();
    mma16_split(Ash, Asl, Bsh, Bsl, wr, wc, acc);
  }
  int l = threadIdx.x & 63;
  int er = wr + ((l >> 4) << 2), ec = wc + (l & 15);
#pragma unroll
  for (int m = 0; m < 4; m++)
#pragma unroll
    for (int n = 0; n < 4; n++)
#pragma unroll
      for (int r = 0; r < 4; r++) {
        float v = acc[m][n][r];
        v = fminf(fmaxf(v, -8.f), 8.f);
        C[(size_t)(row0 + er + m * 16 + r) * QKV_N + col0 + ec + n * 16] = v;
      }
}

// scores -> split bf16 (scaled), causal tiles only
__global__ __launch_bounds__(256) void k_qk_s(const unsigned short* __restrict__ qh,
                                              const unsigned short* __restrict__ ql,
                                              const unsigned short* __restrict__ kh,
                                              const unsigned short* __restrict__ kl,
                                              unsigned short* __restrict__ Sh,
                                              unsigned short* __restrict__ Sl, int hbase) {
  if ((int)blockIdx.x > (int)blockIdx.y) return;
  int z = blockIdx.z;
  int h = hbase + z;
  const unsigned short* Ah = qh + (size_t)h * S_LEN * HD;
  const unsigned short* Al = ql + (size_t)h * S_LEN * HD;
  const unsigned short* Bh = kh + (size_t)(h >> 2) * S_LEN * HD;
  const unsigned short* Bl = kl + (size_t)(h >> 2) * S_LEN * HD;
  __shared__ unsigned short Ash[128 * 32], Asl[128 * 32], Bsh[128 * 32], Bsl[128 * 32];
  int row0 = blockIdx.y * 128, col0 = blockIdx.x * 128;
  int w = threadIdx.x >> 6;
  int wr = (w >> 1) * 64, wc = (w & 1) * 64;
  f32x4 acc[4][4] = {};
  for (int k0 = 0; k0 < HD; k0 += 32) {
    __syncthreads();
    stage_rows(Ah, HD, row0, k0, Ash);
    stage_rows(Al, HD, row0, k0, Asl);
    stage_rows(Bh, HD, col0, k0, Bsh);
    stage_rows(Bl, HD, col0, k0, Bsl);
    __syncthreads();
    mma16_split(Ash, Asl, Bsh, Bsl, wr, wc, acc);
  }
  const float scale = 0.08838834764831845f;  // 1/sqrt(128)
  int l = threadIdx.x & 63;
  int er = wr + ((l >> 4) << 2), ec = wc + (l & 15);
#pragma unroll
  for (int m = 0; m < 4; m++)
#pragma unroll
    for (int n = 0; n < 4; n++)
#pragma unroll
      for (int r = 0; r < 4; r++) {
        float v = acc[m][n][r] * scale;
        size_t idx = ((size_t)z * S_LEN + row0 + er + m * 16 + r) * S_LEN + col0 + ec + n * 16;
        unsigned short hh, ll;
        split2(v, hh, ll);
        Sh[idx] = hh; Sl[idx] = ll;
      }
}

// softmax in fp32 over split rows; writes P split in place (zeros above diagonal)
__global__ __launch_bounds__(256) void k_sm_s(unsigned short* __restrict__ Sh,
                                              unsigned short* __restrict__ Sl) {
  int q = blockIdx.x, z = blockIdx.y;
  size_t base = ((size_t)z * S_LEN + q) * S_LEN;
  int t = threadIdx.x;
  uint4 hv = ((const uint4*)(Sh + base))[t];
  uint4 lv = ((const uint4*)(Sl + base))[t];
  unsigned short* hp = (unsigned short*)&hv;
  unsigned short* lp = (unsigned short*)&lv;
  float v[8];
  float mx = -3.4e38f;
#pragma unroll
  for (int j = 0; j < 8; j++) {
    int c = t * 8 + j;
    float x = bf2f(hp[j]) + bf2f(lp[j]);
    v[j] = x;
    if (c <= q) mx = fmaxf(mx, x);
  }
#pragma unroll
  for (int o = 32; o; o >>= 1) mx = fmaxf(mx, __shfl_down(mx, o));
  __shared__ float red[8];
  int wid = t >> 6;
  if ((t & 63) == 0) red[wid] = mx;
  __syncthreads();
  if (t == 0) red[4] = fmaxf(fmaxf(red[0], red[1]), fmaxf(red[2], red[3]));
  __syncthreads();
  mx = red[4];
  float s = 0.f;
#pragma unroll
  for (int j = 0; j < 8; j++) {
    float e = (t * 8 + j <= q) ? expf(v[j] - mx) : 0.f;
    v[j] = e; s += e;
  }
#pragma unroll
  for (int o = 32; o; o >>= 1) s += __shfl_down(s, o);
  if ((t & 63) == 0) red[wid] = s;
  __syncthreads();
  if (t == 0) red[5] = red[0] + red[1] + red[2] + red[3];
  __syncthreads();
  float inv = 1.f / red[5];
#pragma unroll
  for (int j = 0; j < 8; j++) split2(v[j] * inv, hp[j], lp[j]);
  ((uint4*)(Sh + base))[t] = hv;
  ((uint4*)(Sl + base))[t] = lv;
}

// PV partials: grid (kc, row-tile, head); pvp[z][kc][S][HD] f32
__global__ __launch_bounds__(256) void k_pv(const unsigned short* __restrict__ Ph,
                                            const unsigned short* __restrict__ Pl,
                                            const float* __restrict__ qkv,
                                            float* __restrict__ pvp, int hbase) {
  int kc = blockIdx.x, rt = blockIdx.y, z = blockIdx.z;
  int Keff = (rt + 1) * 128;
  int kbeg = kc * 512;
  if (kbeg >= Keff) return;
  int kend = min(kbeg + 512, Keff);
  int h = hbase + z;
  const unsigned short* Ah = Ph + (size_t)z * S_LEN * S_LEN;
  const unsigned short* Al = Pl + (size_t)z * S_LEN * S_LEN;
  const float* B = qkv + (NH + NKV) * HD + (size_t)(h >> 2) * HD;  // ldb = QKV_N
  __shared__ unsigned short Ash[128 * 32], Asl[128 * 32], Bsh[128 * 32], Bsl[128 * 32];
  int row0 = rt * 128;
  int w = threadIdx.x >> 6;
  int wr = (w >> 1) * 64, wc = (w & 1) * 64;
  f32x4 acc[4][4] = {};
  for (int k0 = kbeg; k0 < kend; k0 += 32) {
    __syncthreads();
    stage_rows(Ah, S_LEN, row0, k0, Ash);
    stage_rows(Al, S_LEN, row0, k0, Asl);
    stage_bT_split(B, QKV_N, k0, 0, Bsh, Bsl);
    __syncthreads();
    mma16_split(Ash, Asl, Bsh, Bsl, wr, wc, acc);
  }
  int l = threadIdx.x & 63;
  int er = wr + ((l >> 4) << 2), ec = wc + (l & 15);
  float* dst = pvp + ((size_t)z * 4 + kc) * S_LEN * HD;
#pragma unroll
  for (int m = 0; m < 4; m++)
#pragma unroll
    for (int n = 0; n < 4; n++)
#pragma unroll
      for (int r = 0; r < 4; r++)
        dst[(size_t)(row0 + er + m * 16 + r) * HD + ec + n * 16] = acc[m][n][r];
}

// reduce partials -> split attn
__global__ __launch_bounds__(256) void k_pvred(const float* __restrict__ pvp,
                                               unsigned short* __restrict__ ath,
                                               unsigned short* __restrict__ atl, int hbase) {
  int idx = blockIdx.x * 256 + threadIdx.x;  // z * S * 32 float4-units
  int c4 = idx & 31;
  int row = (idx >> 5) & (S_LEN - 1);
  int z = idx >> 16;
  int nkc = (row >> 9) + 1;
  const float* src = pvp + (size_t)z * 4 * S_LEN * HD + (size_t)row * HD + c4 * 4;
  float a0 = 0.f, a1 = 0.f, a2 = 0.f, a3 = 0.f;
  for (int j = 0; j < nkc; j++) {
    float4 p = *(const float4*)(src + (size_t)j * S_LEN * HD);
    a0 += p.x; a1 += p.y; a2 += p.z; a3 += p.w;
  }
  size_t o = (size_t)row * DMODEL + (size_t)(hbase + z) * HD + c4 * 4;
  unsigned short hh, ll;
  split2(a0, hh, ll); ath[o] = hh; atl[o] = ll;
  split2(a1, hh, ll); ath[o + 1] = hh; atl[o + 1] = ll;
  split2(a2, hh, ll); ath[o + 2] = hh; atl[o + 2] = ll;
  split2(a3, hh, ll); ath[o + 3] = hh; atl[o + 3] = ll;
}

__global__ __launch_bounds__(256) void k_wo_s(const unsigned short* __restrict__ Ah,
                                              const unsigned short* __restrict__ Al,
                                              const float* __restrict__ B,
                                              const float* __restrict__ resid,
                                              float* __restrict__ x1) {
  __shared__ unsigned short Ash[128 * 32], Asl[128 * 32], Bsh[128 * 32], Bsl[128 * 32];
  int row0 = blockIdx.y * 128, col0 = blockIdx.x * 128;
  int w = threadIdx.x >> 6;
  int wr = (w >> 1) * 64, wc = (w & 1) * 64;
  f32x4 acc[4][4] = {};
  for (int k0 = 0; k0 < DMODEL; k0 += 32) {
    __syncthreads();
    stage_rows(Ah, DMODEL, row0, k0, Ash);
    stage_rows(Al, DMODEL, row0, k0, Asl);
    stage_bT_split(B, DMODEL, k0, col0, Bsh, Bsl);
    __syncthreads();
    mma16_split(Ash, Asl, Bsh, Bsl, wr, wc, acc);
  }
  int l = threadIdx.x & 63;
  int er = wr + ((l >> 4) << 2), ec = wc + (l & 15);
#pragma unroll
  for (int m = 0; m < 4; m++)
#pragma unroll
    for (int n = 0; n < 4; n++)
#pragma unroll
      for (int r = 0; r < 4; r++) {
        size_t idx = (size_t)(row0 + er + m * 16 + r) * DMODEL + col0 + ec + n * 16;
        x1[idx] = resid[idx] + acc[m][n][r];
      }
}

// ---------------- MoE GEMMs (plain bf16, tile-list grid) ----------------

__global__ __launch_bounds__(256) void k_moe1(const unsigned short* __restrict__ h2b,
                                              const float* __restrict__ w1,
                                              const float* __restrict__ v1,
                                              const int* __restrict__ off,
                                              const int* __restrict__ ptok,
                                              const int* __restrict__ meta,
                                              unsigned short* __restrict__ g) {
  int ty = blockIdx.y;
  if (ty >= meta[25]) return;
  int tt = meta[26 + ty];
  int e = tt & 7, m0 = tt >> 3;
  int nvalid = min(128, meta[e] - m0);  // meta[0..7] = cnt
  const int* toks = ptok + off[e] + m0;
  int col0 = blockIdx.x * 128;
  const float* B1 = w1 + (size_t)e * DMODEL * FF;
  const float* B2 = v1 + (size_t)e * DMODEL * FF;
  __shared__ unsigned short As[128 * 32], Bs1[128 * 32], Bs2[128 * 32];
  int w = threadIdx.x >> 6;
  int wr = (w >> 1) * 64, wc = (w & 1) * 64;
  f32x4 acc1[4][4] = {}, acc2[4][4] = {};
  for (int k0 = 0; k0 < DMODEL; k0 += 32) {
    __syncthreads();
    stage_gather(h2b, DMODEL, toks, nvalid, k0, As);
    stage_bT(B1, FF, k0, col0, Bs1);
    stage_bT(B2, FF, k0, col0, Bs2);
    __syncthreads();
    mma16_dual(As, Bs1, Bs2, wr, wc, acc1, acc2);
  }
  int l = threadIdx.x & 63;
  int er = wr + ((l >> 4) << 2), ec = wc + (l & 15);
  size_t gbase = (size_t)off[e] + m0;
#pragma unroll
  for (int m = 0; m < 4; m++)
#pragma unroll
    for (int n = 0; n < 4; n++)
#pragma unroll
      for (int r = 0; r < 4; r++) {
        int rl = er + m * 16 + r;
        if (rl < nvalid) {
          float a = acc1[m][n][r];
          float s = a / (1.f + expf(-a));
          g[(gbase + rl) * FF + col0 + ec + n * 16] = f2bf(s * acc2[m][n][r]);
        }
      }
}

__global__ __launch_bounds__(256) void k_moe2(const unsigned short* __restrict__ g,
                                              const float* __restrict__ w2,
                                              const int* __restrict__ off,
                                              const int* __restrict__ ptok,
                                              const float* __restrict__ pw,
                                              const int* __restrict__ meta,
                                              float* __restrict__ y) {
  int ty = blockIdx.y;
  if (ty >= meta[25]) return;
  int tt = meta[26 + ty];
  int e = tt & 7, m0 = tt >> 3;
  int nvalid = min(128, meta[e] - m0);
  long pbase = (long)off[e] + m0;
  int col0 = blockIdx.x * 128;
  const float* B = w2 + (size_t)e * FF * DMODEL;
  __shared__ unsigned short As[128 * 32], Bs[128 * 32];
  int w = threadIdx.x >> 6;
  int wr = (w >> 1) * 64, wc = (w & 1) * 64;
  f32x4 acc[4][4] = {};
  for (int k0 = 0; k0 < FF; k0 += 32) {
    __syncthreads();
    // rows of g are contiguous slots; reuse gather path with identity via stage_rows
    stage_rows(g, FF, pbase, k0, As);
    stage_bT(B, DMODEL, k0, col0, Bs);
    __syncthreads();
    mma16(As, Bs, wr, wc, acc);
  }
  int l = threadIdx.x & 63;
  int er = wr + ((l >> 4) << 2), ec = wc + (l & 15);
#pragma unroll
  for (int m = 0; m < 4; m++)
#pragma unroll
    for (int n = 0; n < 4; n++)
#pragma unroll
      for (int r = 0; r < 4; r++) {
        int rl = er + m * 16 + r;
        if (rl < nvalid) {
          long p = pbase + rl;
          int tk = ptok[p];
          atomicAdd(&y[(size_t)tk * DMODEL + col0 + ec + n * 16], acc[m][n][r] * pw[p]);
        }
      }
}

// ---------------- small kernels ----------------

__global__ __launch_bounds__(256) void k_ln(const float* __restrict__ x,
                                            const float* __restrict__ w,
                                            unsigned short* __restrict__ obh,
                                            unsigned short* __restrict__ obl,
                                            float* __restrict__ of) {
  int row = blockIdx.x;
  const float* xr = x + (size_t)row * DMODEL;
  float s = 0.f, ss = 0.f;
  for (int c = threadIdx.x; c < DMODEL; c += 256) {
    float v = xr[c];
    s += v; ss += v * v;
  }
#pragma unroll
  for (int o = 32; o; o >>= 1) { s += __shfl_down(s, o); ss += __shfl_down(ss, o); }
  __shared__ float rs[4], rss[4], mu_s, inv_s;
  int wid = threadIdx.x >> 6;
  if ((threadIdx.x & 63) == 0) { rs[wid] = s; rss[wid] = ss; }
  __syncthreads();
  if (threadIdx.x == 0) {
    float S1 = rs[0] + rs[1] + rs[2] + rs[3];
    float S2 = rss[0] + rss[1] + rss[2] + rss[3];
    float mu = S1 / DMODEL;
    mu_s = mu;
    inv_s = rsqrtf(S2 / DMODEL - mu * mu + 1e-5f);
  }
  __syncthreads();
  float mu = mu_s, inv = inv_s;
  for (int c = threadIdx.x; c < DMODEL; c += 256) {
    float v = (xr[c] - mu) * inv * w[c];
    unsigned short hh, ll;
    split2(v, hh, ll);
    obh[(size_t)row * DMODEL + c] = hh;
    if (obl) obl[(size_t)row * DMODEL + c] = ll;
    if (of) of[(size_t)row * DMODEL + c] = v;
  }
}

__global__ void k_rope2(const float* __restrict__ qkv, unsigned short* __restrict__ qh,
                        unsigned short* __restrict__ ql, unsigned short* __restrict__ kh,
                        unsigned short* __restrict__ kl) {
  int t = blockIdx.x;
  int d = threadIdx.x;  // 0..63
  float pf = (float)pow(500000.0, (double)d * (1.0 / 64.0));
  float invf = 1.0f / pf;
  float ang = (float)t * invf;
  float cs = (float)cos((double)ang);
  float sn = (float)sin((double)ang);
  const float* row = qkv + (size_t)t * QKV_N;
  unsigned short hh, ll;
#pragma unroll
  for (int hq = 0; hq < NH; hq++) {
    float a = row[hq * HD + d], b = row[hq * HD + d + 64];
    size_t base = ((size_t)hq * S_LEN + t) * HD;
    split2(a * cs - b * sn, hh, ll); qh[base + d] = hh; ql[base + d] = ll;
    split2(b * cs + a * sn, hh, ll); qh[base + d + 64] = hh; ql[base + d + 64] = ll;
  }
#pragma unroll
  for (int kv = 0; kv < NKV; kv++) {
    float a = row[NH * HD + kv * HD + d], b = row[NH * HD + kv * HD + d + 64];
    size_t base = ((size_t)kv * S_LEN + t) * HD;
    split2(a * cs - b * sn, hh, ll); kh[base + d] = hh; kl[base + d] = ll;
    split2(b * cs + a * sn, hh, ll); kh[base + d + 64] = hh; kl[base + d + 64] = ll;
  }
}

__global__ __launch_bounds__(256) void k_router(const float* __restrict__ h2,
                                                const float* __restrict__ rw,
                                                int* __restrict__ topi,
                                                float* __restrict__ topw,
                                                int* __restrict__ cnt) {
  int t = blockIdx.x;
  __shared__ float hs[DMODEL];
  __shared__ float lg[NE];
  for (int c = threadIdx.x; c < DMODEL; c += 256) hs[c] = h2[(size_t)t * DMODEL + c];
  __syncthreads();
  int grp = threadIdx.x >> 5;
  int ln = threadIdx.x & 31;
  float p = 0.f;
  for (int c = ln; c < DMODEL; c += 32) p += hs[c] * rw[(size_t)grp * DMODEL + c];
#pragma unroll
  for (int o = 16; o; o >>= 1) p += __shfl_down(p, o, 32);
  if (ln == 0) lg[grp] = p;
  __syncthreads();
  if (threadIdx.x == 0) {
    float l0 = -3.4e38f; int i0 = 0;
    for (int e = 0; e < NE; e++)
      if (lg[e] > l0) { l0 = lg[e]; i0 = e; }
    float l1 = -3.4e38f; int i1 = 0;
    for (int e = 0; e < NE; e++)
      if (e != i0 && lg[e] > l1) { l1 = lg[e]; i1 = e; }
    float z = expf(l1 - l0);
    topi[t * 2] = i0; topi[t * 2 + 1] = i1;
    topw[t * 2] = 1.f / (1.f + z); topw[t * 2 + 1] = z / (1.f + z);
    atomicAdd(&cnt[i0], 1);
    atomicAdd(&cnt[i1], 1);
  }
}

// offsets + moe tile list; meta: [0..7]=cnt [8..15]=fill [16..24]=off [25]=ntile [26..]=tiles
__global__ void k_scan(int* __restrict__ meta) {
  if (threadIdx.x == 0 && blockIdx.x == 0) {
    int o = 0, nt = 0;
    for (int e = 0; e < NE; e++) {
      meta[16 + e] = o;
      for (int m0 = 0; m0 < meta[e]; m0 += 128) meta[26 + nt++] = (m0 << 3) | e;
      o += meta[e];
    }
    meta[24] = o;
    meta[25] = nt;
  }
}

__global__ void k_fill(const int* __restrict__ topi, const float* __restrict__ topw,
                       int* __restrict__ meta, int* __restrict__ ptok,
                       float* __restrict__ pw) {
  int t = blockIdx.x * blockDim.x + threadIdx.x;
  if (t >= S_LEN) return;
#pragma unroll
  for (int j = 0; j < 2; j++) {
    int e = topi[t * 2 + j];
    int p = atomicAdd(&meta[8 + e], 1);
    ptok[meta[16 + e] + p] = t;
    pw[meta[16 + e] + p] = topw[t * 2 + j];
  }
}

__global__ void k_final(const float* __restrict__ x1, const float* __restrict__ y,
                        float* __restrict__ out) {
  int i = blockIdx.x * blockDim.x + threadIdx.x;
  float4 a = ((const float4*)x1)[i];
  float4 b = ((const float4*)y)[i];
  ((float4*)out)[i] = make_float4(a.x + b.x, a.y + b.y, a.z + b.z, a.w + b.w);
}

// ---------------- launch ----------------

extern "C" void kernel_launch(void* const* d_in, const int* in_sizes, int n_in,
                              void* d_out, int out_size, void* d_ws, size_t ws_size,
                              hipStream_t stream) {
  (void)in_sizes; (void)n_in; (void)out_size; (void)ws_size;
  const float* x = (const float*)d_in[0];
  const float* ln1w = (const float*)d_in[2];
  const float* ln2w = (const float*)d_in[3];
  const float* wqkv = (const float*)d_in[4];
  const float* wo = (const float*)d_in[5];
  const float* rw = (const float*)d_in[6];
  const float* w1 = (const float*)d_in[7];
  const float* v1 = (const float*)d_in[8];
  const float* w2 = (const float*)d_in[9];
  float* out = (float*)d_out;

  char* wsb = (char*)d_ws;
  const size_t MiB = 1u << 20;
  // phase A: h1 (0..16); phase B: pvp (0..16) over dead h1
  unsigned short* h1h = (unsigned short*)(wsb + 0 * MiB);    // 8 MiB
  unsigned short* h1l = (unsigned short*)(wsb + 8 * MiB);    // 8 MiB
  float* pvp = (float*)(wsb + 0 * MiB);                      // 16 MiB (attn loop)
  float* qkvb = (float*)(wsb + 16 * MiB);                    // 24 MiB
  unsigned short* qh = (unsigned short*)(wsb + 40 * MiB);    // 8 MiB
  unsigned short* ql = (unsigned short*)(wsb + 48 * MiB);    // 8 MiB
  unsigned short* kh = (unsigned short*)(wsb + 56 * MiB);    // 2 MiB
  unsigned short* kl = (unsigned short*)(wsb + 58 * MiB);    // 2 MiB
  unsigned short* Sh = (unsigned short*)(wsb + 60 * MiB);    // 32 MiB [4,S,S]
  unsigned short* Sl = (unsigned short*)(wsb + 92 * MiB);    // 32 MiB
  float* x1 = (float*)(wsb + 60 * MiB);                      // 16 MiB (over dead Sh)
  float* h2f = (float*)(wsb + 76 * MiB);                     // 16 MiB (over dead Sh)
  unsigned short* h2b = (unsigned short*)(wsb + 92 * MiB);   // 8 MiB (over dead Sl)
  unsigned short* g = (unsigned short*)(wsb + 100 * MiB);    // 16 MiB (over dead Sl)
  float* y = (float*)(wsb + 116 * MiB);                      // 16 MiB (over dead Sl/ath)
  unsigned short* ath = (unsigned short*)(wsb + 124 * MiB);  // 8 MiB
  unsigned short* atl = (unsigned short*)(wsb + 132 * MiB);  // 8 MiB
  char* small = wsb + 140 * MiB;
  int* topi = (int*)small;
  float* topw = (float*)(small + 16384);
  int* ptok = (int*)(small + 32768);
  float* pw = (float*)(small + 49152);
  int* meta = (int*)(small + 65536);  // 128 ints

  // ---- attention sublayer (fp32-emulated) ----
  k_ln<<<S_LEN, 256, 0, stream>>>(x, ln1w, h1h, h1l, (float*)nullptr);
  k_qkv_s<<<dim3(QKV_N / 128, S_LEN / 128), 256, 0, stream>>>(h1h, h1l, wqkv, qkvb);
  k_rope2<<<S_LEN, 64, 0, stream>>>(qkvb, qh, ql, kh, kl);
  for (int c = 0; c < 4; c++) {
    k_qk_s<<<dim3(16, 16, 4), 256, 0, stream>>>(qh, ql, kh, kl, Sh, Sl, 4 * c);
    k_sm_s<<<dim3(S_LEN, 4), 256, 0, stream>>>(Sh, Sl);
    k_pv<<<dim3(4, 16, 4), 256, 0, stream>>>(Sh, Sl, qkvb, pvp, 4 * c);
    k_pvred<<<(4 * S_LEN * 32) / 256, 256, 0, stream>>>(pvp, ath, atl, 4 * c);
  }
  k_wo_s<<<dim3(16, 16), 256, 0, stream>>>(ath, atl, wo, x, x1);

  // ---- MoE sublayer ----
  k_ln<<<S_LEN, 256, 0, stream>>>(x1, ln2w, h2b, (unsigned short*)nullptr, h2f);
  hipMemsetAsync(y, 0, (size_t)S_LEN * DMODEL * 4, stream);
  hipMemsetAsync(meta, 0, 512, stream);
  k_router<<<S_LEN, 256, 0, stream>>>(h2f, rw, topi, topw, meta);
  k_scan<<<1, 64, 0, stream>>>(meta);
  k_fill<<<8, 256, 0, stream>>>(topi, topw, meta, ptok, pw);
  k_moe1<<<dim3(16, 40), 256, 0, stream>>>(h2b, w1, v1, meta + 16, ptok, meta, g);
  k_moe2<<<dim3(16, 40), 256, 0, stream>>>(g, w2, meta + 16, ptok, pw, meta, y);
  k_final<<<(S_LEN * DMODEL / 4) / 256, 256, 0, stream>>>(x1, y, out);
}

// Round 4
// 1094.216 us; speedup vs baseline: 2.1191x; 1.0726x over previous
//
#include <hip/hip_runtime.h>

#define S_LEN 2048
#define DMODEL 2048
#define NH 16
#define NKV 4
#define HD 128
#define NE 8
#define FF 2048
#define QKV_N 3072   // (H + 2*KV) * HD

typedef __attribute__((ext_vector_type(8))) short short8;
typedef __attribute__((ext_vector_type(4))) float f32x4;

__device__ inline unsigned short f2bf(float f) {
  unsigned int u = __builtin_bit_cast(unsigned int, f);
  u += 0x7fffu + ((u >> 16) & 1u);
  return (unsigned short)(u >> 16);
}
__device__ inline float bf2f(unsigned short h) {
  unsigned int u = ((unsigned int)h) << 16;
  return __builtin_bit_cast(float, u);
}
__device__ inline void split2(float v, unsigned short& h, unsigned short& l) {
  h = f2bf(v);
  l = f2bf(v - bf2f(h));
}

// ======== LDS tile: [128 rows][32 k] bf16, XOR-quad swizzle (round-3 verified) ========

__device__ inline void stage_rows(const unsigned short* __restrict__ src, int ld,
                                  long row0, int k0, unsigned short* dst) {
  int t = threadIdx.x;
  int r = t >> 2, q = t & 3;
  int s = (r ^ (r >> 2)) & 3;
  uint4 v0 = *(const uint4*)(src + (size_t)(row0 + r) * ld + k0 + q * 8);
  uint4 v1 = *(const uint4*)(src + (size_t)(row0 + r + 64) * ld + k0 + q * 8);
  *(uint4*)(dst + r * 32 + ((q ^ s) << 3)) = v0;
  *(uint4*)(dst + (r + 64) * 32 + ((q ^ s) << 3)) = v1;
}

// register prefetch halves: contiguous rows
__device__ inline void loadA2_rows(const unsigned short* __restrict__ src, int ld,
                                   long row0, int k0, uint4 va[2]) {
  int t = threadIdx.x;
  int r = t >> 2, q = t & 3;
  va[0] = *(const uint4*)(src + (size_t)(row0 + r) * ld + k0 + q * 8);
  va[1] = *(const uint4*)(src + (size_t)(row0 + r + 64) * ld + k0 + q * 8);
}
// gathered rows
__device__ inline void loadA2_g(const unsigned short* __restrict__ src, int ld,
                                const int* __restrict__ toks, int nvalid, int k0,
                                uint4 va[2]) {
  int t = threadIdx.x;
  int r = t >> 2, q = t & 3;
#pragma unroll
  for (int rr = 0; rr < 2; rr++) {
    int row = r + rr * 64;
    uint4 v = make_uint4(0, 0, 0, 0);
    if (row < nvalid) v = *(const uint4*)(src + (size_t)toks[row] * ld + k0 + q * 8);
    va[rr] = v;
  }
}
__device__ inline void writeA2(const uint4 va[2], unsigned short* dst) {
  int t = threadIdx.x;
  int r = t >> 2, q = t & 3;
  int s = (r ^ (r >> 2)) & 3;
  *(uint4*)(dst + r * 32 + ((q ^ s) << 3)) = va[0];
  *(uint4*)(dst + (r + 64) * 32 + ((q ^ s) << 3)) = va[1];
}

// fp32 strided B (k-gather) prefetch halves
__device__ inline void loadB16(const float* __restrict__ B, long ldb, int k0, int n0,
                               float vb[16]) {
  int t = threadIdx.x;
  int n = t & 127, kg = t >> 7;
  const float* p = B + (size_t)(k0 + kg * 16) * ldb + n0 + n;
#pragma unroll
  for (int i = 0; i < 16; i++) vb[i] = p[(size_t)i * ldb];
}
__device__ inline void writeB16(const float vb[16], unsigned short* dst) {
  int t = threadIdx.x;
  int n = t & 127, kg = t >> 7;
  unsigned short hb[16] __attribute__((aligned(16)));
#pragma unroll
  for (int i = 0; i < 16; i++) hb[i] = f2bf(vb[i]);
  int s = (n ^ (n >> 2)) & 3;
  int base = n * 32;
  *(uint4*)(dst + base + (((kg * 2) ^ s) << 3)) = ((const uint4*)hb)[0];
  *(uint4*)(dst + base + (((kg * 2 + 1) ^ s) << 3)) = ((const uint4*)hb)[1];
}

// ---------------- MFMA cores ----------------

__device__ inline void mma16(const unsigned short* As, const unsigned short* Bs,
                             int wr, int wc, f32x4 acc[4][4]) {
  int l = threadIdx.x & 63;
  int lr = l & 15, lg = l >> 4;
  int qoff = ((lg ^ ((lr ^ (lr >> 2)) & 3)) << 3);
  short8 a[4], b[4];
#pragma unroll
  for (int m = 0; m < 4; m++)
    a[m] = *(const short8*)(As + (wr + m * 16 + lr) * 32 + qoff);
#pragma unroll
  for (int n = 0; n < 4; n++)
    b[n] = *(const short8*)(Bs + (wc + n * 16 + lr) * 32 + qoff);
#pragma unroll
  for (int m = 0; m < 4; m++)
#pragma unroll
    for (int n = 0; n < 4; n++)
      acc[m][n] = __builtin_amdgcn_mfma_f32_16x16x32_bf16(a[m], b[n], acc[m][n], 0, 0, 0);
}

// split product with fragment reuse: acc += Ah*Bh + Ah*Bl + Al*Bh
__device__ inline void mma16_split_reg(const unsigned short* Ash, const unsigned short* Asl,
                                       const unsigned short* Bsh, const unsigned short* Bsl,
                                       int wr, int wc, f32x4 acc[4][4]) {
  int l = threadIdx.x & 63;
  int lr = l & 15, lg = l >> 4;
  int qoff = ((lg ^ ((lr ^ (lr >> 2)) & 3)) << 3);
  short8 ah[4], al[4], bh[4], bl[4];
#pragma unroll
  for (int m = 0; m < 4; m++) {
    ah[m] = *(const short8*)(Ash + (wr + m * 16 + lr) * 32 + qoff);
    al[m] = *(const short8*)(Asl + (wr + m * 16 + lr) * 32 + qoff);
  }
#pragma unroll
  for (int n = 0; n < 4; n++) {
    bh[n] = *(const short8*)(Bsh + (wc + n * 16 + lr) * 32 + qoff);
    bl[n] = *(const short8*)(Bsl + (wc + n * 16 + lr) * 32 + qoff);
  }
#pragma unroll
  for (int m = 0; m < 4; m++)
#pragma unroll
    for (int n = 0; n < 4; n++) {
      acc[m][n] = __builtin_amdgcn_mfma_f32_16x16x32_bf16(ah[m], bh[n], acc[m][n], 0, 0, 0);
      acc[m][n] = __builtin_amdgcn_mfma_f32_16x16x32_bf16(ah[m], bl[n], acc[m][n], 0, 0, 0);
      acc[m][n] = __builtin_amdgcn_mfma_f32_16x16x32_bf16(al[m], bh[n], acc[m][n], 0, 0, 0);
    }
}

// ---------------- pre-pass: tiled transpose + split to bf16 hi/lo ----------------
// src f32 [K rows][ld cols] (+ z*zs), out Th/Tl bf16 [N][ldT] (+ z*zd)
__global__ __launch_bounds__(256) void k_tsplit(const float* __restrict__ src, long ld,
                                                long zs, unsigned short* __restrict__ Th,
                                                unsigned short* __restrict__ Tl, long ldT,
                                                long zd) {
  __shared__ float tile[64][65];
  src += (long)blockIdx.z * zs;
  long k0 = (long)blockIdx.y * 64, n0 = (long)blockIdx.x * 64;
  int r = threadIdx.x >> 2, c4 = (threadIdx.x & 3) << 4;
  const float* p = src + (k0 + r) * ld + n0 + c4;
#pragma unroll
  for (int i = 0; i < 16; i += 4) {
    float4 v = *(const float4*)(p + i);
    tile[r][c4 + i] = v.x;
    tile[r][c4 + i + 1] = v.y;
    tile[r][c4 + i + 2] = v.z;
    tile[r][c4 + i + 3] = v.w;
  }
  __syncthreads();
  unsigned short hb[16] __attribute__((aligned(16)));
  unsigned short lb[16] __attribute__((aligned(16)));
#pragma unroll
  for (int i = 0; i < 16; i++) split2(tile[c4 + i][r], hb[i], lb[i]);
  size_t o = (size_t)blockIdx.z * zd + (size_t)(n0 + r) * ldT + k0 + c4;
  ((uint4*)(Th + o))[0] = ((const uint4*)hb)[0];
  ((uint4*)(Th + o))[1] = ((const uint4*)hb)[1];
  ((uint4*)(Tl + o))[0] = ((const uint4*)lb)[0];
  ((uint4*)(Tl + o))[1] = ((const uint4*)lb)[1];
}

// ---------------- attention-path GEMMs (fp32-emulated, all-bf16 staging) ----------------

__global__ __launch_bounds__(256) void k_qkv_s(const unsigned short* __restrict__ Ah,
                                               const unsigned short* __restrict__ Al,
                                               const unsigned short* __restrict__ BTh,
                                               const unsigned short* __restrict__ BTl,
                                               float* __restrict__ C) {
  __shared__ unsigned short Ash[128 * 32], Asl[128 * 32], Bsh[128 * 32], Bsl[128 * 32];
  int row0 = blockIdx.y * 128, col0 = blockIdx.x * 128;
  int w = threadIdx.x >> 6;
  int wr = (w >> 1) * 64, wc = (w & 1) * 64;
  f32x4 acc[4][4] = {};
  for (int k0 = 0; k0 < DMODEL; k0 += 32) {
    __syncthreads();
    stage_rows(Ah, DMODEL, row0, k0, Ash);
    stage_rows(Al, DMODEL, row0, k0, Asl);
    stage_rows(BTh, DMODEL, col0, k0, Bsh);
    stage_rows(BTl, DMODEL, col0, k0, Bsl);
    __syncthreads();
    mma16_split_reg(Ash, Asl, Bsh, Bsl, wr, wc, acc);
  }
  int l = threadIdx.x & 63;
  int er = wr + ((l >> 4) << 2), ec = wc + (l & 15);
#pragma unroll
  for (int m = 0; m < 4; m++)
#pragma unroll
    for (int n = 0; n < 4; n++)
#pragma unroll
      for (int r = 0; r < 4; r++) {
        float v = acc[m][n][r];
        v = fminf(fmaxf(v, -8.f), 8.f);
        C[(size_t)(row0 + er + m * 16 + r) * QKV_N + col0 + ec + n * 16] = v;
      }
}

__global__ __launch_bounds__(256) void k_qk_s(const unsigned short* __restrict__ qh,
                                              const unsigned short* __restrict__ ql,
                                              const unsigned short* __restrict__ kh,
                                              const unsigned short* __restrict__ kl,
                                              unsigned short* __restrict__ Sh,
                                              unsigned short* __restrict__ Sl, int hbase) {
  if ((int)blockIdx.x > (int)blockIdx.y) return;
  int z = blockIdx.z;
  int h = hbase + z;
  const unsigned short* Ah = qh + (size_t)h * S_LEN * HD;
  const unsigned short* Al = ql + (size_t)h * S_LEN * HD;
  const unsigned short* Bh = kh + (size_t)(h >> 2) * S_LEN * HD;
  const unsigned short* Bl = kl + (size_t)(h >> 2) * S_LEN * HD;
  __shared__ unsigned short Ash[128 * 32], Asl[128 * 32], Bsh[128 * 32], Bsl[128 * 32];
  int row0 = blockIdx.y * 128, col0 = blockIdx.x * 128;
  int w = threadIdx.x >> 6;
  int wr = (w >> 1) * 64, wc = (w & 1) * 64;
  f32x4 acc[4][4] = {};
  for (int k0 = 0; k0 < HD; k0 += 32) {
    __syncthreads();
    stage_rows(Ah, HD, row0, k0, Ash);
    stage_rows(Al, HD, row0, k0, Asl);
    stage_rows(Bh, HD, col0, k0, Bsh);
    stage_rows(Bl, HD, col0, k0, Bsl);
    __syncthreads();
    mma16_split_reg(Ash, Asl, Bsh, Bsl, wr, wc, acc);
  }
  const float scale = 0.08838834764831845f;  // 1/sqrt(128)
  int l = threadIdx.x & 63;
  int er = wr + ((l >> 4) << 2), ec = wc + (l & 15);
#pragma unroll
  for (int m = 0; m < 4; m++)
#pragma unroll
    for (int n = 0; n < 4; n++)
#pragma unroll
      for (int r = 0; r < 4; r++) {
        float v = acc[m][n][r] * scale;
        size_t idx = ((size_t)z * S_LEN + row0 + er + m * 16 + r) * S_LEN + col0 + ec + n * 16;
        unsigned short hh, ll;
        split2(v, hh, ll);
        Sh[idx] = hh; Sl[idx] = ll;
      }
}

__global__ __launch_bounds__(256) void k_sm_s(unsigned short* __restrict__ Sh,
                                              unsigned short* __restrict__ Sl) {
  int q = blockIdx.x, z = blockIdx.y;
  size_t base = ((size_t)z * S_LEN + q) * S_LEN;
  int t = threadIdx.x;
  uint4 hv = ((const uint4*)(Sh + base))[t];
  uint4 lv = ((const uint4*)(Sl + base))[t];
  unsigned short* hp = (unsigned short*)&hv;
  unsigned short* lp = (unsigned short*)&lv;
  float v[8];
  float mx = -3.4e38f;
#pragma unroll
  for (int j = 0; j < 8; j++) {
    int c = t * 8 + j;
    float x = bf2f(hp[j]) + bf2f(lp[j]);
    v[j] = x;
    if (c <= q) mx = fmaxf(mx, x);
  }
#pragma unroll
  for (int o = 32; o; o >>= 1) mx = fmaxf(mx, __shfl_down(mx, o));
  __shared__ float red[8];
  int wid = t >> 6;
  if ((t & 63) == 0) red[wid] = mx;
  __syncthreads();
  if (t == 0) red[4] = fmaxf(fmaxf(red[0], red[1]), fmaxf(red[2], red[3]));
  __syncthreads();
  mx = red[4];
  float s = 0.f;
#pragma unroll
  for (int j = 0; j < 8; j++) {
    float e = (t * 8 + j <= q) ? expf(v[j] - mx) : 0.f;
    v[j] = e; s += e;
  }
#pragma unroll
  for (int o = 32; o; o >>= 1) s += __shfl_down(s, o);
  if ((t & 63) == 0) red[wid] = s;
  __syncthreads();
  if (t == 0) red[5] = red[0] + red[1] + red[2] + red[3];
  __syncthreads();
  float inv = 1.f / red[5];
#pragma unroll
  for (int j = 0; j < 8; j++) split2(v[j] * inv, hp[j], lp[j]);
  ((uint4*)(Sh + base))[t] = hv;
  ((uint4*)(Sl + base))[t] = lv;
}

// PV partials from pretransposed split V
__global__ __launch_bounds__(256) void k_pv(const unsigned short* __restrict__ Ph,
                                            const unsigned short* __restrict__ Pl,
                                            const unsigned short* __restrict__ vTh,
                                            const unsigned short* __restrict__ vTl,
                                            float* __restrict__ pvp, int hbase) {
  int kc = blockIdx.x, rt = blockIdx.y, z = blockIdx.z;
  int Keff = (rt + 1) * 128;
  int kbeg = kc * 512;
  if (kbeg >= Keff) return;
  int kend = min(kbeg + 512, Keff);
  int h = hbase + z;
  const unsigned short* Ah = Ph + (size_t)z * S_LEN * S_LEN;
  const unsigned short* Al = Pl + (size_t)z * S_LEN * S_LEN;
  const unsigned short* Bh = vTh + (size_t)(h >> 2) * HD * S_LEN;
  const unsigned short* Bl = vTl + (size_t)(h >> 2) * HD * S_LEN;
  __shared__ unsigned short Ash[128 * 32], Asl[128 * 32], Bsh[128 * 32], Bsl[128 * 32];
  int row0 = rt * 128;
  int w = threadIdx.x >> 6;
  int wr = (w >> 1) * 64, wc = (w & 1) * 64;
  f32x4 acc[4][4] = {};
  for (int k0 = kbeg; k0 < kend; k0 += 32) {
    __syncthreads();
    stage_rows(Ah, S_LEN, row0, k0, Ash);
    stage_rows(Al, S_LEN, row0, k0, Asl);
    stage_rows(Bh, S_LEN, 0, k0, Bsh);
    stage_rows(Bl, S_LEN, 0, k0, Bsl);
    __syncthreads();
    mma16_split_reg(Ash, Asl, Bsh, Bsl, wr, wc, acc);
  }
  int l = threadIdx.x & 63;
  int er = wr + ((l >> 4) << 2), ec = wc + (l & 15);
  float* dst = pvp + ((size_t)z * 4 + kc) * S_LEN * HD;
#pragma unroll
  for (int m = 0; m < 4; m++)
#pragma unroll
    for (int n = 0; n < 4; n++)
#pragma unroll
      for (int r = 0; r < 4; r++)
        dst[(size_t)(row0 + er + m * 16 + r) * HD + ec + n * 16] = acc[m][n][r];
}

__global__ __launch_bounds__(256) void k_pvred(const float* __restrict__ pvp,
                                               unsigned short* __restrict__ ath,
                                               unsigned short* __restrict__ atl, int hbase) {
  int idx = blockIdx.x * 256 + threadIdx.x;
  int c4 = idx & 31;
  int row = (idx >> 5) & (S_LEN - 1);
  int z = idx >> 16;
  int nkc = (row >> 9) + 1;
  const float* src = pvp + (size_t)z * 4 * S_LEN * HD + (size_t)row * HD + c4 * 4;
  float a0 = 0.f, a1 = 0.f, a2 = 0.f, a3 = 0.f;
  for (int j = 0; j < nkc; j++) {
    float4 p = *(const float4*)(src + (size_t)j * S_LEN * HD);
    a0 += p.x; a1 += p.y; a2 += p.z; a3 += p.w;
  }
  size_t o = (size_t)row * DMODEL + (size_t)(hbase + z) * HD + c4 * 4;
  unsigned short hh, ll;
  split2(a0, hh, ll); ath[o] = hh; atl[o] = ll;
  split2(a1, hh, ll); ath[o + 1] = hh; atl[o + 1] = ll;
  split2(a2, hh, ll); ath[o + 2] = hh; atl[o + 2] = ll;
  split2(a3, hh, ll); ath[o + 3] = hh; atl[o + 3] = ll;
}

__global__ __launch_bounds__(256) void k_wo_s(const unsigned short* __restrict__ Ah,
                                              const unsigned short* __restrict__ Al,
                                              const unsigned short* __restrict__ BTh,
                                              const unsigned short* __restrict__ BTl,
                                              const float* __restrict__ resid,
                                              float* __restrict__ x1) {
  __shared__ unsigned short Ash[128 * 32], Asl[128 * 32], Bsh[128 * 32], Bsl[128 * 32];
  int row0 = blockIdx.y * 128, col0 = blockIdx.x * 128;
  int w = threadIdx.x >> 6;
  int wr = (w >> 1) * 64, wc = (w & 1) * 64;
  f32x4 acc[4][4] = {};
  for (int k0 = 0; k0 < DMODEL; k0 += 32) {
    __syncthreads();
    stage_rows(Ah, DMODEL, row0, k0, Ash);
    stage_rows(Al, DMODEL, row0, k0, Asl);
    stage_rows(BTh, DMODEL, col0, k0, Bsh);
    stage_rows(BTl, DMODEL, col0, k0, Bsl);
    __syncthreads();
    mma16_split_reg(Ash, Asl, Bsh, Bsl, wr, wc, acc);
  }
  int l = threadIdx.x & 63;
  int er = wr + ((l >> 4) << 2), ec = wc + (l & 15);
#pragma unroll
  for (int m = 0; m < 4; m++)
#pragma unroll
    for (int n = 0; n < 4; n++)
#pragma unroll
      for (int r = 0; r < 4; r++) {
        size_t idx = (size_t)(row0 + er + m * 16 + r) * DMODEL + col0 + ec + n * 16;
        x1[idx] = resid[idx] + acc[m][n][r];
      }
}

// ---------------- MoE GEMMs: single-acc, register double-buffer prefetch ----------------

// a1 = h2 @ w1[e]  (raw preact, f32)
__global__ __launch_bounds__(256) void k_moe_w1(const unsigned short* __restrict__ h2b,
                                                const float* __restrict__ w1,
                                                const int* __restrict__ off,
                                                const int* __restrict__ ptok,
                                                const int* __restrict__ meta,
                                                float* __restrict__ a1) {
  int ty = blockIdx.y;
  if (ty >= meta[25]) return;
  int tt = meta[26 + ty];
  int e = tt & 7, m0 = tt >> 3;
  int nvalid = min(128, meta[e] - m0);
  const int* toks = ptok + off[e] + m0;
  int col0 = blockIdx.x * 128;
  const float* B = w1 + (size_t)e * DMODEL * FF;
  __shared__ unsigned short As[128 * 32], Bs[128 * 32];
  int w = threadIdx.x >> 6;
  int wr = (w >> 1) * 64, wc = (w & 1) * 64;
  uint4 va[2];
  float vb[16];
  loadA2_g(h2b, DMODEL, toks, nvalid, 0, va);
  loadB16(B, FF, 0, col0, vb);
  f32x4 acc[4][4] = {};
  for (int kt = 0; kt < DMODEL / 32; kt++) {
    writeA2(va, As);
    writeB16(vb, Bs);
    __syncthreads();
    if (kt + 1 < DMODEL / 32) {
      loadA2_g(h2b, DMODEL, toks, nvalid, (kt + 1) * 32, va);
      loadB16(B, FF, (kt + 1) * 32, col0, vb);
    }
    mma16(As, Bs, wr, wc, acc);
    __syncthreads();
  }
  int l = threadIdx.x & 63;
  int er = wr + ((l >> 4) << 2), ec = wc + (l & 15);
  size_t gbase = (size_t)off[e] + m0;
#pragma unroll
  for (int m = 0; m < 4; m++)
#pragma unroll
    for (int n = 0; n < 4; n++)
#pragma unroll
      for (int r = 0; r < 4; r++) {
        int rl = er + m * 16 + r;
        if (rl < nvalid)
          a1[(gbase + rl) * FF + col0 + ec + n * 16] = acc[m][n][r];
      }
}

// g = silu(a1) * (h2 @ v1[e])
__global__ __launch_bounds__(256) void k_moe_v1g(const unsigned short* __restrict__ h2b,
                                                 const float* __restrict__ v1,
                                                 const float* __restrict__ a1,
                                                 const int* __restrict__ off,
                                                 const int* __restrict__ ptok,
                                                 const int* __restrict__ meta,
                                                 unsigned short* __restrict__ g) {
  int ty = blockIdx.y;
  if (ty >= meta[25]) return;
  int tt = meta[26 + ty];
  int e = tt & 7, m0 = tt >> 3;
  int nvalid = min(128, meta[e] - m0);
  const int* toks = ptok + off[e] + m0;
  int col0 = blockIdx.x * 128;
  const float* B = v1 + (size_t)e * DMODEL * FF;
  __shared__ unsigned short As[128 * 32], Bs[128 * 32];
  int w = threadIdx.x >> 6;
  int wr = (w >> 1) * 64, wc = (w & 1) * 64;
  uint4 va[2];
  float vb[16];
  loadA2_g(h2b, DMODEL, toks, nvalid, 0, va);
  loadB16(B, FF, 0, col0, vb);
  f32x4 acc[4][4] = {};
  for (int kt = 0; kt < DMODEL / 32; kt++) {
    writeA2(va, As);
    writeB16(vb, Bs);
    __syncthreads();
    if (kt + 1 < DMODEL / 32) {
      loadA2_g(h2b, DMODEL, toks, nvalid, (kt + 1) * 32, va);
      loadB16(B, FF, (kt + 1) * 32, col0, vb);
    }
    mma16(As, Bs, wr, wc, acc);
    __syncthreads();
  }
  int l = threadIdx.x & 63;
  int er = wr + ((l >> 4) << 2), ec = wc + (l & 15);
  size_t gbase = (size_t)off[e] + m0;
#pragma unroll
  for (int m = 0; m < 4; m++)
#pragma unroll
    for (int n = 0; n < 4; n++)
#pragma unroll
      for (int r = 0; r < 4; r++) {
        int rl = er + m * 16 + r;
        if (rl < nvalid) {
          size_t idx = (gbase + rl) * FF + col0 + ec + n * 16;
          float av = a1[idx];
          float s = av / (1.f + expf(-av));
          g[idx] = f2bf(s * acc[m][n][r]);
        }
      }
}

// y[tok] += gate * (g @ w2[e])
__global__ __launch_bounds__(256) void k_moe2(const unsigned short* __restrict__ g,
                                              const float* __restrict__ w2,
                                              const int* __restrict__ off,
                                              const int* __restrict__ ptok,
                                              const float* __restrict__ pw,
                                              const int* __restrict__ meta,
                                              float* __restrict__ y) {
  int ty = blockIdx.y;
  if (ty >= meta[25]) return;
  int tt = meta[26 + ty];
  int e = tt & 7, m0 = tt >> 3;
  int nvalid = min(128, meta[e] - m0);
  long pbase = (long)off[e] + m0;
  int col0 = blockIdx.x * 128;
  const float* B = w2 + (size_t)e * FF * DMODEL;
  __shared__ unsigned short As[128 * 32], Bs[128 * 32];
  int w = threadIdx.x >> 6;
  int wr = (w >> 1) * 64, wc = (w & 1) * 64;
  uint4 va[2];
  float vb[16];
  loadA2_rows(g, FF, pbase, 0, va);
  loadB16(B, DMODEL, 0, col0, vb);
  f32x4 acc[4][4] = {};
  for (int kt = 0; kt < FF / 32; kt++) {
    writeA2(va, As);
    writeB16(vb, Bs);
    __syncthreads();
    if (kt + 1 < FF / 32) {
      loadA2_rows(g, FF, pbase, (kt + 1) * 32, va);
      loadB16(B, DMODEL, (kt + 1) * 32, col0, vb);
    }
    mma16(As, Bs, wr, wc, acc);
    __syncthreads();
  }
  int l = threadIdx.x & 63;
  int er = wr + ((l >> 4) << 2), ec = wc + (l & 15);
#pragma unroll
  for (int m = 0; m < 4; m++)
#pragma unroll
    for (int n = 0; n < 4; n++)
#pragma unroll
      for (int r = 0; r < 4; r++) {
        int rl = er + m * 16 + r;
        if (rl < nvalid) {
          long p = pbase + rl;
          int tk = ptok[p];
          atomicAdd(&y[(size_t)tk * DMODEL + col0 + ec + n * 16], acc[m][n][r] * pw[p]);
        }
      }
}

// ---------------- small kernels ----------------

__global__ __launch_bounds__(256) void k_ln(const float* __restrict__ x,
                                            const float* __restrict__ w,
                                            unsigned short* __restrict__ obh,
                                            unsigned short* __restrict__ obl,
                                            float* __restrict__ of) {
  int row = blockIdx.x;
  const float* xr = x + (size_t)row * DMODEL;
  float s = 0.f, ss = 0.f;
  for (int c = threadIdx.x; c < DMODEL; c += 256) {
    float v = xr[c];
    s += v; ss += v * v;
  }
#pragma unroll
  for (int o = 32; o; o >>= 1) { s += __shfl_down(s, o); ss += __shfl_down(ss, o); }
  __shared__ float rs[4], rss[4], mu_s, inv_s;
  int wid = threadIdx.x >> 6;
  if ((threadIdx.x & 63) == 0) { rs[wid] = s; rss[wid] = ss; }
  __syncthreads();
  if (threadIdx.x == 0) {
    float S1 = rs[0] + rs[1] + rs[2] + rs[3];
    float S2 = rss[0] + rss[1] + rss[2] + rss[3];
    float mu = S1 / DMODEL;
    mu_s = mu;
    inv_s = rsqrtf(S2 / DMODEL - mu * mu + 1e-5f);
  }
  __syncthreads();
  float mu = mu_s, inv = inv_s;
  for (int c = threadIdx.x; c < DMODEL; c += 256) {
    float v = (xr[c] - mu) * inv * w[c];
    unsigned short hh, ll;
    split2(v, hh, ll);
    obh[(size_t)row * DMODEL + c] = hh;
    if (obl) obl[(size_t)row * DMODEL + c] = ll;
    if (of) of[(size_t)row * DMODEL + c] = v;
  }
}

__global__ void k_rope2(const float* __restrict__ qkv, unsigned short* __restrict__ qh,
                        unsigned short* __restrict__ ql, unsigned short* __restrict__ kh,
                        unsigned short* __restrict__ kl) {
  int t = blockIdx.x;
  int d = threadIdx.x;  // 0..63
  float pf = (float)pow(500000.0, (double)d * (1.0 / 64.0));
  float invf = 1.0f / pf;
  float ang = (float)t * invf;
  float cs = (float)cos((double)ang);
  float sn = (float)sin((double)ang);
  const float* row = qkv + (size_t)t * QKV_N;
  unsigned short hh, ll;
#pragma unroll
  for (int hq = 0; hq < NH; hq++) {
    float a = row[hq * HD + d], b = row[hq * HD + d + 64];
    size_t base = ((size_t)hq * S_LEN + t) * HD;
    split2(a * cs - b * sn, hh, ll); qh[base + d] = hh; ql[base + d] = ll;
    split2(b * cs + a * sn, hh, ll); qh[base + d + 64] = hh; ql[base + d + 64] = ll;
  }
#pragma unroll
  for (int kv = 0; kv < NKV; kv++) {
    float a = row[NH * HD + kv * HD + d], b = row[NH * HD + kv * HD + d + 64];
    size_t base = ((size_t)kv * S_LEN + t) * HD;
    split2(a * cs - b * sn, hh, ll); kh[base + d] = hh; kl[base + d] = ll;
    split2(b * cs + a * sn, hh, ll); kh[base + d + 64] = hh; kl[base + d + 64] = ll;
  }
}

__global__ __launch_bounds__(256) void k_router(const float* __restrict__ h2,
                                                const float* __restrict__ rw,
                                                int* __restrict__ topi,
                                                float* __restrict__ topw,
                                                int* __restrict__ cnt) {
  int t = blockIdx.x;
  __shared__ float hs[DMODEL];
  __shared__ float lg[NE];
  for (int c = threadIdx.x; c < DMODEL; c += 256) hs[c] = h2[(size_t)t * DMODEL + c];
  __syncthreads();
  int grp = threadIdx.x >> 5;
  int ln = threadIdx.x & 31;
  float p = 0.f;
  for (int c = ln; c < DMODEL; c += 32) p += hs[c] * rw[(size_t)grp * DMODEL + c];
#pragma unroll
  for (int o = 16; o; o >>= 1) p += __shfl_down(p, o, 32);
  if (ln == 0) lg[grp] = p;
  __syncthreads();
  if (threadIdx.x == 0) {
    float l0 = -3.4e38f; int i0 = 0;
    for (int e = 0; e < NE; e++)
      if (lg[e] > l0) { l0 = lg[e]; i0 = e; }
    float l1 = -3.4e38f; int i1 = 0;
    for (int e = 0; e < NE; e++)
      if (e != i0 && lg[e] > l1) { l1 = lg[e]; i1 = e; }
    float z = expf(l1 - l0);
    topi[t * 2] = i0; topi[t * 2 + 1] = i1;
    topw[t * 2] = 1.f / (1.f + z); topw[t * 2 + 1] = z / (1.f + z);
    atomicAdd(&cnt[i0], 1);
    atomicAdd(&cnt[i1], 1);
  }
}

__global__ void k_scan(int* __restrict__ meta) {
  if (threadIdx.x == 0 && blockIdx.x == 0) {
    int o = 0, nt = 0;
    for (int e = 0; e < NE; e++) {
      meta[16 + e] = o;
      for (int m0 = 0; m0 < meta[e]; m0 += 128) meta[26 + nt++] = (m0 << 3) | e;
      o += meta[e];
    }
    meta[24] = o;
    meta[25] = nt;
  }
}

__global__ void k_fill(const int* __restrict__ topi, const float* __restrict__ topw,
                       int* __restrict__ meta, int* __restrict__ ptok,
                       float* __restrict__ pw) {
  int t = blockIdx.x * blockDim.x + threadIdx.x;
  if (t >= S_LEN) return;
#pragma unroll
  for (int j = 0; j < 2; j++) {
    int e = topi[t * 2 + j];
    int p = atomicAdd(&meta[8 + e], 1);
    ptok[meta[16 + e] + p] = t;
    pw[meta[16 + e] + p] = topw[t * 2 + j];
  }
}

__global__ void k_final(const float* __restrict__ x1, const float* __restrict__ y,
                        float* __restrict__ out) {
  int i = blockIdx.x * blockDim.x + threadIdx.x;
  float4 a = ((const float4*)x1)[i];
  float4 b = ((const float4*)y)[i];
  ((float4*)out)[i] = make_float4(a.x + b.x, a.y + b.y, a.z + b.z, a.w + b.w);
}

// ---------------- launch ----------------

extern "C" void kernel_launch(void* const* d_in, const int* in_sizes, int n_in,
                              void* d_out, int out_size, void* d_ws, size_t ws_size,
                              hipStream_t stream) {
  (void)in_sizes; (void)n_in; (void)out_size; (void)ws_size;
  const float* x = (const float*)d_in[0];
  const float* ln1w = (const float*)d_in[2];
  const float* ln2w = (const float*)d_in[3];
  const float* wqkv = (const float*)d_in[4];
  const float* wo = (const float*)d_in[5];
  const float* rw = (const float*)d_in[6];
  const float* w1 = (const float*)d_in[7];
  const float* v1 = (const float*)d_in[8];
  const float* w2 = (const float*)d_in[9];
  float* out = (float*)d_out;

  char* wsb = (char*)d_ws;
  const size_t MiB = 1u << 20;
  // attention phase
  unsigned short* h1h = (unsigned short*)(wsb + 0 * MiB);      // 8
  unsigned short* h1l = (unsigned short*)(wsb + 8 * MiB);      // 8
  float* qkvb = (float*)(wsb + 16 * MiB);                      // 24
  unsigned short* qh = (unsigned short*)(wsb + 40 * MiB);      // 8
  unsigned short* ql = (unsigned short*)(wsb + 48 * MiB);      // 8
  unsigned short* kh = (unsigned short*)(wsb + 56 * MiB);      // 2
  unsigned short* kl = (unsigned short*)(wsb + 58 * MiB);      // 2
  unsigned short* vTh = (unsigned short*)(wsb + 60 * MiB);     // 2
  unsigned short* vTl = (unsigned short*)(wsb + 62 * MiB);     // 2
  unsigned short* Sh = (unsigned short*)(wsb + 64 * MiB);      // 32
  unsigned short* Sl = (unsigned short*)(wsb + 96 * MiB);      // 32
  unsigned short* ath = (unsigned short*)(wsb + 128 * MiB);    // 8
  unsigned short* atl = (unsigned short*)(wsb + 136 * MiB);    // 8
  unsigned short* wqkvTh = (unsigned short*)(wsb + 144 * MiB); // 12
  unsigned short* wqkvTl = (unsigned short*)(wsb + 156 * MiB); // 12
  unsigned short* woTh = (unsigned short*)(wsb + 168 * MiB);   // 8
  unsigned short* woTl = (unsigned short*)(wsb + 176 * MiB);   // 8
  float* pvp = (float*)(wsb + 0 * MiB);                        // 16 (over dead h1)
  // MoE phase (over dead attention buffers)
  float* x1 = (float*)(wsb + 16 * MiB);                        // 16 (over qkvb)
  float* h2f = (float*)(wsb + 32 * MiB);                       // 16 (over qkvb/qh)
  unsigned short* h2b = (unsigned short*)(wsb + 48 * MiB);     // 8 (over ql)
  float* a1 = (float*)(wsb + 64 * MiB);                        // 32 (over Sh)
  unsigned short* g = (unsigned short*)(wsb + 96 * MiB);       // 16 (over Sl)
  float* y = (float*)(wsb + 112 * MiB);                        // 16 (over Sl)
  char* small = wsb + 184 * MiB;
  int* topi = (int*)small;
  float* topw = (float*)(small + 16384);
  int* ptok = (int*)(small + 32768);
  float* pw = (float*)(small + 49152);
  int* meta = (int*)(small + 65536);

  // ---- pre-pass: weight transpose+split ----
  k_tsplit<<<dim3(QKV_N / 64, DMODEL / 64, 1), 256, 0, stream>>>(
      wqkv, QKV_N, 0, wqkvTh, wqkvTl, DMODEL, 0);
  k_tsplit<<<dim3(DMODEL / 64, DMODEL / 64, 1), 256, 0, stream>>>(
      wo, DMODEL, 0, woTh, woTl, DMODEL, 0);

  // ---- attention sublayer (fp32-emulated) ----
  k_ln<<<S_LEN, 256, 0, stream>>>(x, ln1w, h1h, h1l, (float*)nullptr);
  k_qkv_s<<<dim3(QKV_N / 128, S_LEN / 128), 256, 0, stream>>>(h1h, h1l, wqkvTh, wqkvTl, qkvb);
  k_rope2<<<S_LEN, 64, 0, stream>>>(qkvb, qh, ql, kh, kl);
  k_tsplit<<<dim3(HD / 64, S_LEN / 64, NKV), 256, 0, stream>>>(
      qkvb + (NH + NKV) * HD, QKV_N, HD, vTh, vTl, S_LEN, (long)HD * S_LEN);
  for (int c = 0; c < 4; c++) {
    k_qk_s<<<dim3(16, 16, 4), 256, 0, stream>>>(qh, ql, kh, kl, Sh, Sl, 4 * c);
    k_sm_s<<<dim3(S_LEN, 4), 256, 0, stream>>>(Sh, Sl);
    k_pv<<<dim3(4, 16, 4), 256, 0, stream>>>(Sh, Sl, vTh, vTl, pvp, 4 * c);
    k_pvred<<<(4 * S_LEN * 32) / 256, 256, 0, stream>>>(pvp, ath, atl, 4 * c);
  }
  k_wo_s<<<dim3(16, 16), 256, 0, stream>>>(ath, atl, woTh, woTl, x, x1);

  // ---- MoE sublayer ----
  k_ln<<<S_LEN, 256, 0, stream>>>(x1, ln2w, h2b, (unsigned short*)nullptr, h2f);
  hipMemsetAsync(y, 0, (size_t)S_LEN * DMODEL * 4, stream);
  hipMemsetAsync(meta, 0, 512, stream);
  k_router<<<S_LEN, 256, 0, stream>>>(h2f, rw, topi, topw, meta);
  k_scan<<<1, 64, 0, stream>>>(meta);
  k_fill<<<8, 256, 0, stream>>>(topi, topw, meta, ptok, pw);
  k_moe_w1<<<dim3(16, 40), 256, 0, stream>>>(h2b, w1, meta + 16, ptok, meta, a1);
  k_moe_v1g<<<dim3(16, 40), 256, 0, stream>>>(h2b, v1, a1, meta + 16, ptok, meta, g);
  k_moe2<<<dim3(16, 40), 256, 0, stream>>>(g, w2, meta + 16, ptok, pw, meta, y);
  k_final<<<(S_LEN * DMODEL / 4) / 256, 256, 0, stream>>>(x1, y, out);
}